// Round 8
// baseline (3538.034 us; speedup 1.0000x reference)
//
#include <hip/hip_runtime.h>
#include <hip/hip_bf16.h>

#define T_   32
#define B_   32
#define NIN_ 512
#define H_   1024
#define NOUT_ 256
#define NBLK 16
#define NTHR 512
#define NCOL 64
#define NSLOT 80

typedef short bf16x8 __attribute__((ext_vector_type(8)));
typedef float f32x4  __attribute__((ext_vector_type(4)));

__device__ __forceinline__ float bf2f(unsigned short u) {
  union { unsigned int i; float f; } x; x.i = ((unsigned int)u) << 16; return x.f;
}
__device__ __forceinline__ unsigned short f2bf(float f) {
  __hip_bfloat16 h = __float2bfloat16(f);
  return *reinterpret_cast<unsigned short*>(&h);
}
// pack f32 -> (bf16_hi << 16) | bf16_lo   (hi+lo ~= v to ~2^-16 rel)
__device__ __forceinline__ unsigned int packf(float v) {
  unsigned short h = f2bf(v);
  unsigned short l = f2bf(v - bf2f(h));
  return ((unsigned int)h << 16) | l;
}
// 8 packed u32 -> hi/lo bf16x8 fragments
__device__ __forceinline__ void unpack8(const unsigned int* t, bf16x8& hi, bf16x8& lo) {
  union { bf16x8 v; unsigned int u[4]; } H, L;
#pragma unroll
  for (int j = 0; j < 4; j++) {
    unsigned int a = t[2 * j], b = t[2 * j + 1];
    H.u[j] = (b & 0xFFFF0000u) | (a >> 16);
    L.u[j] = (b << 16) | (a & 0xFFFFu);
  }
  hi = H.v; lo = L.v;
}

// ---- coherent (cache-bypassing) primitives ----
__device__ __forceinline__ void astu(unsigned int* p, unsigned int v) {
  __hip_atomic_store(p, v, __ATOMIC_RELAXED, __HIP_MEMORY_SCOPE_AGENT);
}
__device__ __forceinline__ void astf(float* p, float v) {
  __hip_atomic_store(p, v, __ATOMIC_RELAXED, __HIP_MEMORY_SCOPE_AGENT);
}
__device__ __forceinline__ float aldf(const float* p) {
  return __hip_atomic_load((float*)p, __ATOMIC_RELAXED, __HIP_MEMORY_SCOPE_AGENT);
}
__device__ __forceinline__ void aaddf(float* p, float v) {
  __hip_atomic_fetch_add(p, v, __ATOMIC_RELAXED, __HIP_MEMORY_SCOPE_AGENT);
}
__device__ __forceinline__ void coh_unpack8(const unsigned int* p, bf16x8& hi, bf16x8& lo) {
  unsigned int t[8];
#pragma unroll
  for (int j = 0; j < 4; j++) {
    unsigned long long w = __hip_atomic_load((unsigned long long*)(p + 2 * j),
                                             __ATOMIC_RELAXED, __HIP_MEMORY_SCOPE_AGENT);
    t[2 * j] = (unsigned int)w;
    t[2 * j + 1] = (unsigned int)(w >> 32);
  }
  unpack8(t, hi, lo);
}

// ---- rendezvous: fresh slot; release add, relaxed spin (proven R7) ----
__device__ __forceinline__ void rendezvous(int* cnt, int slot) {
  __syncthreads();
  if (threadIdx.x == 0) {
    __hip_atomic_fetch_add(&cnt[slot], 1, __ATOMIC_RELEASE, __HIP_MEMORY_SCOPE_AGENT);
    while (__hip_atomic_load(&cnt[slot], __ATOMIC_RELAXED, __HIP_MEMORY_SCOPE_AGENT) < NBLK)
      __builtin_amdgcn_s_sleep(2);
    __atomic_signal_fence(__ATOMIC_ACQUIRE);
  }
  __syncthreads();
}

// ---------- dtype detect + counter init ----------
__global__ void init_detect(const unsigned short* __restrict__ x_raw,
                            int* __restrict__ flag, int* __restrict__ cnt) {
  __shared__ int bad;
  if (threadIdx.x == 0) bad = 0;
  __syncthreads();
  int c = 0;
  for (int i = threadIdx.x; i < 2048; i += 256) {
    float v = bf2f(x_raw[i]);
    if (!(fabsf(v) < 1e9f)) c++;
  }
  if (c) atomicAdd(&bad, 1);
  __syncthreads();
  if (threadIdx.x == 0) flag[0] = bad ? 1 : 0;  // 1 = inputs are f32
  for (int i = threadIdx.x; i < NSLOT; i += 256)
    __hip_atomic_store(&cnt[i], 0, __ATOMIC_RELAXED, __HIP_MEMORY_SCOPE_AGENT);
}

// ---------- x -> relu + pack ----------
__global__ void pack_relu_x(const void* __restrict__ src, unsigned int* __restrict__ dst,
                            int n, const int* __restrict__ flag) {
  bool isf32 = flag[0] != 0;
  for (int i = blockIdx.x * 256 + threadIdx.x; i < n; i += gridDim.x * 256) {
    float v = isf32 ? ((const float*)src)[i] : bf2f(((const unsigned short*)src)[i]);
    dst[i] = packf(fmaxf(v, 0.f));
  }
}

// ---------- params -> float: [lam, eta, g[1024], b[1024]] ----------
__global__ void prep_params(const void* lam, const void* eta, const void* g, const void* b,
                            float* __restrict__ par, const int* __restrict__ flag) {
  bool isf32 = flag[0] != 0;
  int t = blockIdx.x * 256 + threadIdx.x;
  if (t == 0) {
    par[0] = isf32 ? ((const float*)lam)[0] : bf2f(((const unsigned short*)lam)[0]);
    par[1] = isf32 ? ((const float*)eta)[0] : bf2f(((const unsigned short*)eta)[0]);
  }
  if (t < H_) {
    par[2 + t]      = isf32 ? ((const float*)g)[t] : bf2f(((const unsigned short*)g)[t]);
    par[2 + H_ + t] = isf32 ? ((const float*)b)[t] : bf2f(((const unsigned short*)b)[t]);
  }
}

// ---------- transpose + hi/lo split: W [R][C] -> bf16 [C][R] ----------
__global__ void split_transpose(const void* __restrict__ in,
                                unsigned short* __restrict__ out_hi,
                                unsigned short* __restrict__ out_lo,
                                int R, int C, const int* __restrict__ flag) {
  __shared__ unsigned short thi[32][33], tlo[32][33];
  bool isf32 = flag[0] != 0;
  int c0 = blockIdx.x * 32, r0 = blockIdx.y * 32;
  int tx = threadIdx.x & 31, ty = threadIdx.x >> 5;
  for (int i = ty; i < 32; i += 8) {
    size_t idx = (size_t)(r0 + i) * C + c0 + tx;
    float v = isf32 ? ((const float*)in)[idx] : bf2f(((const unsigned short*)in)[idx]);
    unsigned short h = f2bf(v);
    thi[i][tx] = h;
    tlo[i][tx] = f2bf(v - bf2f(h));
  }
  __syncthreads();
  for (int i = ty; i < 32; i += 8) {
    out_hi[(size_t)(c0 + i) * R + r0 + tx] = thi[tx][i];
    out_lo[(size_t)(c0 + i) * R + r0 + tx] = tlo[tx][i];
  }
}

// ---------- phase-A GEMM on packed A: out = relu+pack (OUTMODE=1) or f32 (0) ----------
template<int K, int N, int OUTMODE>
__global__ void gemmA_pk(const unsigned int* __restrict__ A,
                         const unsigned short* __restrict__ BT_hi,
                         const unsigned short* __restrict__ BT_lo,
                         void* __restrict__ C) {
  int wave = (blockIdx.x * blockDim.x + threadIdx.x) >> 6;
  int lane = threadIdx.x & 63;
  const int ntj = N >> 4;
  int mt = wave / ntj, jt = wave - mt * ntj;
  int col = lane & 15, quad = lane >> 4;
  const unsigned int*   ap = A     + (size_t)(mt * 16 + col) * K + quad * 8;
  const unsigned short* bh = BT_hi + (size_t)(jt * 16 + col) * K + quad * 8;
  const unsigned short* bl = BT_lo + (size_t)(jt * 16 + col) * K + quad * 8;
  f32x4 acc = {0.f, 0.f, 0.f, 0.f};
#pragma unroll 4
  for (int kk = 0; kk < K; kk += 32) {
    bf16x8 ahi, alo;
    unpack8(ap + kk, ahi, alo);
    bf16x8 vh = *(const bf16x8*)(bh + kk);
    bf16x8 vl = *(const bf16x8*)(bl + kk);
    acc = __builtin_amdgcn_mfma_f32_16x16x32_bf16(ahi, vh, acc, 0, 0, 0);
    acc = __builtin_amdgcn_mfma_f32_16x16x32_bf16(alo, vh, acc, 0, 0, 0);
    acc = __builtin_amdgcn_mfma_f32_16x16x32_bf16(ahi, vl, acc, 0, 0, 0);
  }
#pragma unroll
  for (int r = 0; r < 4; r++) {
    size_t idx = (size_t)(mt * 16 + quad * 4 + r) * N + jt * 16 + col;
    if (OUTMODE) ((unsigned int*)C)[idx] = packf(fmaxf(acc[r], 0.f));
    else         ((float*)C)[idx] = acc[r];
  }
}

// ---- 16x16 MFMA tile; A packed u32 (coherent), row stride H_ ----
__device__ __forceinline__ f32x4 mm_tile_pk(
    const unsigned int* __restrict__ A, int am0,
    const unsigned short* __restrict__ BH, const unsigned short* __restrict__ BL,
    int bj0, f32x4 acc, int col, int quad) {
  const unsigned int*   ap = A  + (size_t)(am0 + col) * H_ + quad * 8;
  const unsigned short* bh = BH + (size_t)(bj0 + col) * H_ + quad * 8;
  const unsigned short* bl = BL + (size_t)(bj0 + col) * H_ + quad * 8;
#pragma unroll 8
  for (int kk = 0; kk < H_; kk += 32) {
    bf16x8 ahi, alo;
    coh_unpack8(ap + kk, ahi, alo);
    bf16x8 vh = *(const bf16x8*)(bh + kk);
    bf16x8 vl = *(const bf16x8*)(bl + kk);
    acc = __builtin_amdgcn_mfma_f32_16x16x32_bf16(ahi, vh, acc, 0, 0, 0);
    acc = __builtin_amdgcn_mfma_f32_16x16x32_bf16(alo, vh, acc, 0, 0, 0);
    acc = __builtin_amdgcn_mfma_f32_16x16x32_bf16(ahi, vl, acc, 0, 0, 0);
  }
  return acc;
}

// ---------- recurrent: 16 blocks x 512 thr x 64 cols, packed-h communication ----------
__global__ void __launch_bounds__(NTHR) recurrent(
    const unsigned short* __restrict__ WhT_hi, const unsigned short* __restrict__ WhT_lo,
    const unsigned short* __restrict__ WhoT_hi, const unsigned short* __restrict__ WhoT_lo,
    const unsigned short* __restrict__ WoT_hi, const unsigned short* __restrict__ WoT_lo,
    const float* __restrict__ ZC,
    unsigned int* __restrict__ hpk,   // [B][H] packed h_cur (coherent)
    unsigned int* __restrict__ hpt,   // [B][H] packed h_t (coherent)
    unsigned int* __restrict__ Opub,  // [B][H] packed o (coherent)
    float* __restrict__ hist_loc,     // [NBLK][T][B][NCOL] block-private f32
    float* __restrict__ dots_g,       // [T][B][T] coherent atomicAdd
    const float* __restrict__ par,
    void* __restrict__ y_out,
    int* __restrict__ cnt,
    const int* __restrict__ flag)
{
  __shared__ float lds_hs[B_][NCOL + 1];
  __shared__ float lds_dt[B_][T_];
  __shared__ float lds_mu[NCOL], lds_sc[NCOL], lds_bb[NCOL];

  const int tid = threadIdx.x, wg = blockIdx.x;
  const int wv = tid >> 6, lane = tid & 63;
  const int col = lane & 15, quad = lane >> 4;
  const int j0 = wg * NCOL;
  const int bt = wv >> 2, ct = wv & 3;       // batch-half, col-tile
  const int am0 = bt * 16;
  const int cl0 = ct * 16;
  const int jg0 = j0 + cl0;
  const float lam = par[0], eta = par[1];
  const bool isf32 = flag[0] != 0;
  float* hl = hist_loc + (size_t)wg * (T_ * B_ * NCOL);

  // zero h_cur slice + dots slice
  for (int i = tid; i < B_ * H_ / NBLK; i += NTHR)
    astu(hpk + (size_t)wg * (B_ * H_ / NBLK) + i, 0u);
  for (int i = tid; i < T_ * B_ * T_ / NBLK; i += NTHR)
    astf(dots_g + (size_t)wg * (T_ * B_ * T_ / NBLK) + i, 0.f);
  rendezvous(cnt, 0);

  int slot = 1;
  for (int t = 0; t < T_; ++t) {
    const float* zb = ZC + (size_t)t * B_ * H_;
    // ---- stage 1: h_t = relu(zc + h_cur @ W_h), own cols ----
    {
      f32x4 acc;
#pragma unroll
      for (int r = 0; r < 4; r++)
        acc[r] = zb[(size_t)(am0 + quad * 4 + r) * H_ + jg0 + col];
      acc = mm_tile_pk(hpk, am0, WhT_hi, WhT_lo, jg0, acc, col, quad);
#pragma unroll
      for (int r = 0; r < 4; r++) {
        float v = fmaxf(acc[r], 0.f);
        int m = am0 + quad * 4 + r;
        hl[((size_t)t * B_ + m) * NCOL + cl0 + col] = v;
        astu(hpt + (size_t)m * H_ + jg0 + col, packf(v));
      }
    }
    __syncthreads();
    // ---- partial dots over own cols -> atomicAdd ----
    for (int d = tid; d < B_ * (t + 1); d += NTHR) {
      int b = d / (t + 1), s = d - b * (t + 1);
      const f32x4* p = (const f32x4*)(hl + ((size_t)t * B_ + b) * NCOL);
      const f32x4* q = (const f32x4*)(hl + ((size_t)s * B_ + b) * NCOL);
      float sum = 0.f;
#pragma unroll
      for (int i = 0; i < 16; i++) {
        f32x4 a = p[i], c = q[i];
        sum += a[0] * c[0] + a[1] * c[1] + a[2] * c[2] + a[3] * c[3];
      }
      aaddf(dots_g + ((size_t)t * B_ + b) * T_ + s, sum);
    }
    rendezvous(cnt, slot++);
    // ---- stage dots into LDS; hs GEMM tile ----
    for (int d = tid; d < B_ * (t + 1); d += NTHR) {
      int b = d / (t + 1), s = d - b * (t + 1);
      lds_dt[b][s] = aldf(dots_g + ((size_t)t * B_ + b) * T_ + s);
    }
    {
      f32x4 acc;
#pragma unroll
      for (int r = 0; r < 4; r++)
        acc[r] = zb[(size_t)(am0 + quad * 4 + r) * H_ + jg0 + col];
      acc = mm_tile_pk(hpt, am0, WhT_hi, WhT_lo, jg0, acc, col, quad);
#pragma unroll
      for (int r = 0; r < 4; r++) lds_hs[am0 + quad * 4 + r][cl0 + col] = acc[r];
    }
    __syncthreads();
    // ---- attention: += eta * sum_s lam^(t-s) dots[b][s] * hl[s][b][c] ----
    for (int d = tid; d < B_ * NCOL; d += NTHR) {
      int b = d >> 6, c = d & 63;
      float a = 0.f, w = eta;
      const float* hb = hl + (size_t)b * NCOL + c;
      for (int s = t; s >= 0; --s) {
        a += w * lds_dt[b][s] * hb[(size_t)s * B_ * NCOL];
        w *= lam;
      }
      lds_hs[b][c] += a;
    }
    __syncthreads();
    // ---- batch-norm (block-local) ----
    if (tid < NCOL) {
      int c = tid;
      float sum = 0.f;
#pragma unroll
      for (int b = 0; b < B_; b++) sum += lds_hs[b][c];
      float mu = sum * (1.f / B_);
      float sq = 0.f;
#pragma unroll
      for (int b = 0; b < B_; b++) {
        float dd = lds_hs[b][c] - mu;
        sq += dd * dd;
      }
      float sig = sqrtf(sq * (1.f / B_));
      lds_mu[c] = mu;
      lds_sc[c] = par[2 + j0 + c] / sig;
      lds_bb[c] = par[2 + H_ + j0 + c];
    }
    __syncthreads();
    // ---- apply + publish h_cur slice (packed) ----
    for (int d = tid; d < B_ * NCOL; d += NTHR) {
      int b = d >> 6, c = d & 63;
      float v = (lds_hs[b][c] - lds_mu[c]) * lds_sc[c] + lds_bb[c];
      astu(hpk + (size_t)b * H_ + j0 + c, packf(fmaxf(v, 0.f)));
    }
    rendezvous(cnt, slot++);
  }
  // ---- o = relu(h_cur @ W_ho), own cols ----
  {
    f32x4 acc = {0.f, 0.f, 0.f, 0.f};
    acc = mm_tile_pk(hpk, am0, WhoT_hi, WhoT_lo, jg0, acc, col, quad);
#pragma unroll
    for (int r = 0; r < 4; r++)
      astu(Opub + (size_t)(am0 + quad * 4 + r) * H_ + jg0 + col, packf(fmaxf(acc[r], 0.f)));
  }
  rendezvous(cnt, slot++);
  // ---- y = relu(o @ W_o): 32 tiles on blocks 0..3 ----
  if (wg < 4) {
    int id = wg * 8 + wv;             // 0..31
    int bt2 = id & 1, jt2 = id >> 1;  // jt2 0..15
    f32x4 acc = {0.f, 0.f, 0.f, 0.f};
    acc = mm_tile_pk(Opub, bt2 * 16, WoT_hi, WoT_lo, jt2 * 16, acc, col, quad);
#pragma unroll
    for (int r = 0; r < 4; r++) {
      float v = fmaxf(acc[r], 0.f);
      size_t idx = (size_t)(bt2 * 16 + quad * 4 + r) * NOUT_ + jt2 * 16 + col;
      if (isf32) ((float*)y_out)[idx] = v;
      else       ((unsigned short*)y_out)[idx] = f2bf(v);
    }
  }
}

extern "C" void kernel_launch(void* const* d_in, const int* in_sizes, int n_in,
                              void* d_out, int out_size, void* d_ws, size_t ws_size,
                              hipStream_t stream) {
  const void* x_in = d_in[0];
  const void* W_i  = d_in[1];
  const void* W_z  = d_in[2];
  const void* W_c  = d_in[3];
  const void* W_h  = d_in[4];
  const void* W_ho = d_in[5];
  const void* W_o  = d_in[6];
  const void* lam  = d_in[7];
  const void* eta  = d_in[8];
  const void* g    = d_in[9];
  const void* bb   = d_in[10];

  char* wsp = (char*)d_ws;
  size_t off = 0;
  auto alloc = [&](size_t bytes) {
    void* p = wsp + off;
    off += (bytes + 255) & ~(size_t)255;
    return p;
  };
  int*            flag    = (int*)alloc(16);
  int*            cnt     = (int*)alloc(NSLOT * 4);
  float*          par     = (float*)alloc((2 + 2 * H_) * 4);
  unsigned int*   X_pk    = (unsigned int*)alloc((size_t)T_ * B_ * NIN_ * 4);
  unsigned short* WiT_hi  = (unsigned short*)alloc((size_t)NIN_ * H_ * 2);
  unsigned short* WiT_lo  = (unsigned short*)alloc((size_t)NIN_ * H_ * 2);
  unsigned short* WzT_hi  = (unsigned short*)alloc((size_t)H_ * H_ * 2);
  unsigned short* WzT_lo  = (unsigned short*)alloc((size_t)H_ * H_ * 2);
  unsigned short* WcT_hi  = (unsigned short*)alloc((size_t)H_ * H_ * 2);
  unsigned short* WcT_lo  = (unsigned short*)alloc((size_t)H_ * H_ * 2);
  unsigned short* WhT_hi  = (unsigned short*)alloc((size_t)H_ * H_ * 2);
  unsigned short* WhT_lo  = (unsigned short*)alloc((size_t)H_ * H_ * 2);
  unsigned short* WhoT_hi = (unsigned short*)alloc((size_t)H_ * H_ * 2);
  unsigned short* WhoT_lo = (unsigned short*)alloc((size_t)H_ * H_ * 2);
  unsigned short* WoT_hi  = (unsigned short*)alloc((size_t)H_ * NOUT_ * 2);
  unsigned short* WoT_lo  = (unsigned short*)alloc((size_t)H_ * NOUT_ * 2);
  unsigned int*   S_pk    = (unsigned int*)alloc((size_t)T_ * B_ * H_ * 4);
  unsigned int*   Z_pk    = (unsigned int*)alloc((size_t)T_ * B_ * H_ * 4);
  float*          ZC      = (float*)alloc((size_t)T_ * B_ * H_ * 4);
  unsigned int*   hpk     = (unsigned int*)alloc((size_t)B_ * H_ * 4);
  unsigned int*   hpt     = (unsigned int*)alloc((size_t)B_ * H_ * 4);
  unsigned int*   Opub    = (unsigned int*)alloc((size_t)B_ * H_ * 4);
  float*          histloc = (float*)alloc((size_t)NBLK * T_ * B_ * NCOL * 4);
  float*          dots_g  = (float*)alloc((size_t)T_ * B_ * T_ * 4);
  (void)ws_size; (void)in_sizes; (void)n_in; (void)out_size;

  // 1. detect dtype + zero counters; x -> relu+pack; params
  init_detect<<<1, 256, 0, stream>>>((const unsigned short*)x_in, flag, cnt);
  pack_relu_x<<<256, 256, 0, stream>>>(x_in, X_pk, T_ * B_ * NIN_, flag);
  prep_params<<<4, 256, 0, stream>>>(lam, eta, g, bb, par, flag);

  // 2. transpose + hi/lo split weights -> bf16 [N][K]
  split_transpose<<<dim3(H_ / 32, NIN_ / 32), 256, 0, stream>>>(W_i, WiT_hi, WiT_lo, NIN_, H_, flag);
  split_transpose<<<dim3(H_ / 32, H_ / 32), 256, 0, stream>>>(W_z, WzT_hi, WzT_lo, H_, H_, flag);
  split_transpose<<<dim3(H_ / 32, H_ / 32), 256, 0, stream>>>(W_c, WcT_hi, WcT_lo, H_, H_, flag);
  split_transpose<<<dim3(H_ / 32, H_ / 32), 256, 0, stream>>>(W_h, WhT_hi, WhT_lo, H_, H_, flag);
  split_transpose<<<dim3(H_ / 32, H_ / 32), 256, 0, stream>>>(W_ho, WhoT_hi, WhoT_lo, H_, H_, flag);
  split_transpose<<<dim3(NOUT_ / 32, H_ / 32), 256, 0, stream>>>(W_o, WoT_hi, WoT_lo, H_, NOUT_, flag);

  // 3. phase A (packed): S = relu(X@W_i); Z = relu(S@W_z); ZC = Z@W_c (f32)
  gemmA_pk<NIN_, H_, 1><<<1024, 256, 0, stream>>>(X_pk, WiT_hi, WiT_lo, S_pk);
  gemmA_pk<H_,   H_, 1><<<1024, 256, 0, stream>>>(S_pk, WzT_hi, WzT_lo, Z_pk);
  gemmA_pk<H_,   H_, 0><<<1024, 256, 0, stream>>>(Z_pk, WcT_hi, WcT_lo, ZC);

  // 4. phase B: recurrence + readout, packed-h coherence-free kernel
  recurrent<<<NBLK, NTHR, 0, stream>>>(WhT_hi, WhT_lo, WhoT_hi, WhoT_lo, WoT_hi, WoT_lo,
                                       ZC, hpk, hpt, Opub, histloc, dots_g,
                                       par, d_out, cnt, flag);
}

// Round 9
// 1900.093 us; speedup vs baseline: 1.8620x; 1.8620x over previous
//
#include <hip/hip_runtime.h>
#include <hip/hip_bf16.h>

#define T_   32
#define B_   32
#define NIN_ 512
#define H_   1024
#define NOUT_ 256
#define NBLK 32
#define NTHR 256
#define NCOL 32
#define NSLOT 80

typedef short bf16x8 __attribute__((ext_vector_type(8)));
typedef float f32x4  __attribute__((ext_vector_type(4)));
typedef unsigned int u32x4 __attribute__((ext_vector_type(4)));

__device__ __forceinline__ float bf2f(unsigned short u) {
  union { unsigned int i; float f; } x; x.i = ((unsigned int)u) << 16; return x.f;
}
__device__ __forceinline__ unsigned short f2bf(float f) {
  __hip_bfloat16 h = __float2bfloat16(f);
  return *reinterpret_cast<unsigned short*>(&h);
}
// pack f32 -> (bf16_hi << 16) | bf16_lo
__device__ __forceinline__ unsigned int packf(float v) {
  unsigned short h = f2bf(v);
  unsigned short l = f2bf(v - bf2f(h));
  return ((unsigned int)h << 16) | l;
}
// 8 packed u32 (two u32x4) -> hi/lo bf16x8
__device__ __forceinline__ void unpack8v(u32x4 a, u32x4 b, bf16x8& hi, bf16x8& lo) {
  unsigned int t[8] = {a[0], a[1], a[2], a[3], b[0], b[1], b[2], b[3]};
  union { bf16x8 v; unsigned int u[4]; } H, L;
#pragma unroll
  for (int j = 0; j < 4; j++) {
    unsigned int e = t[2 * j], o = t[2 * j + 1];
    H.u[j] = (o & 0xFFFF0000u) | (e >> 16);
    L.u[j] = (o << 16) | (e & 0xFFFFu);
  }
  hi = H.v; lo = L.v;
}

// ---- publish primitives: relaxed agent-scope atomics (bypass L2 to coherent point) ----
__device__ __forceinline__ void astu(unsigned int* p, unsigned int v) {
  __hip_atomic_store(p, v, __ATOMIC_RELAXED, __HIP_MEMORY_SCOPE_AGENT);
}
__device__ __forceinline__ void astf(float* p, float v) {
  __hip_atomic_store(p, v, __ATOMIC_RELAXED, __HIP_MEMORY_SCOPE_AGENT);
}
__device__ __forceinline__ void aaddf(float* p, float v) {
  __hip_atomic_fetch_add(p, v, __ATOMIC_RELAXED, __HIP_MEMORY_SCOPE_AGENT);
}

// ---- rendezvous: fresh slot; release add, relaxed spin (no L2 invalidate) ----
__device__ __forceinline__ void rendezvous(int* cnt, int slot) {
  __syncthreads();
  if (threadIdx.x == 0) {
    __hip_atomic_fetch_add(&cnt[slot], 1, __ATOMIC_RELEASE, __HIP_MEMORY_SCOPE_AGENT);
    while (__hip_atomic_load(&cnt[slot], __ATOMIC_RELAXED, __HIP_MEMORY_SCOPE_AGENT) < NBLK)
      __builtin_amdgcn_s_sleep(1);
    __atomic_signal_fence(__ATOMIC_ACQUIRE);
  }
  __syncthreads();
}

// ---------- dtype detect + counter init ----------
__global__ void init_detect(const unsigned short* __restrict__ x_raw,
                            int* __restrict__ flag, int* __restrict__ cnt) {
  __shared__ int bad;
  if (threadIdx.x == 0) bad = 0;
  __syncthreads();
  int c = 0;
  for (int i = threadIdx.x; i < 2048; i += 256) {
    float v = bf2f(x_raw[i]);
    if (!(fabsf(v) < 1e9f)) c++;
  }
  if (c) atomicAdd(&bad, 1);
  __syncthreads();
  if (threadIdx.x == 0) flag[0] = bad ? 1 : 0;  // 1 = inputs are f32
  for (int i = threadIdx.x; i < NSLOT; i += 256)
    __hip_atomic_store(&cnt[i], 0, __ATOMIC_RELAXED, __HIP_MEMORY_SCOPE_AGENT);
}

// ---------- x -> relu + pack ----------
__global__ void pack_relu_x(const void* __restrict__ src, unsigned int* __restrict__ dst,
                            int n, const int* __restrict__ flag) {
  bool isf32 = flag[0] != 0;
  for (int i = blockIdx.x * 256 + threadIdx.x; i < n; i += gridDim.x * 256) {
    float v = isf32 ? ((const float*)src)[i] : bf2f(((const unsigned short*)src)[i]);
    dst[i] = packf(fmaxf(v, 0.f));
  }
}

// ---------- params -> float: [lam, eta, g[1024], b[1024]] ----------
__global__ void prep_params(const void* lam, const void* eta, const void* g, const void* b,
                            float* __restrict__ par, const int* __restrict__ flag) {
  bool isf32 = flag[0] != 0;
  int t = blockIdx.x * 256 + threadIdx.x;
  if (t == 0) {
    par[0] = isf32 ? ((const float*)lam)[0] : bf2f(((const unsigned short*)lam)[0]);
    par[1] = isf32 ? ((const float*)eta)[0] : bf2f(((const unsigned short*)eta)[0]);
  }
  if (t < H_) {
    par[2 + t]      = isf32 ? ((const float*)g)[t] : bf2f(((const unsigned short*)g)[t]);
    par[2 + H_ + t] = isf32 ? ((const float*)b)[t] : bf2f(((const unsigned short*)b)[t]);
  }
}

// ---------- transpose + hi/lo split: W [R][C] -> bf16 [C][R] ----------
__global__ void split_transpose(const void* __restrict__ in,
                                unsigned short* __restrict__ out_hi,
                                unsigned short* __restrict__ out_lo,
                                int R, int C, const int* __restrict__ flag) {
  __shared__ unsigned short thi[32][33], tlo[32][33];
  bool isf32 = flag[0] != 0;
  int c0 = blockIdx.x * 32, r0 = blockIdx.y * 32;
  int tx = threadIdx.x & 31, ty = threadIdx.x >> 5;
  for (int i = ty; i < 32; i += 8) {
    size_t idx = (size_t)(r0 + i) * C + c0 + tx;
    float v = isf32 ? ((const float*)in)[idx] : bf2f(((const unsigned short*)in)[idx]);
    unsigned short h = f2bf(v);
    thi[i][tx] = h;
    tlo[i][tx] = f2bf(v - bf2f(h));
  }
  __syncthreads();
  for (int i = ty; i < 32; i += 8) {
    out_hi[(size_t)(c0 + i) * R + r0 + tx] = thi[tx][i];
    out_lo[(size_t)(c0 + i) * R + r0 + tx] = tlo[tx][i];
  }
}

// ---------- phase-A GEMM on packed A: out = relu+pack (1) or f32 (0) ----------
template<int K, int N, int OUTMODE>
__global__ void gemmA_pk(const unsigned int* __restrict__ A,
                         const unsigned short* __restrict__ BT_hi,
                         const unsigned short* __restrict__ BT_lo,
                         void* __restrict__ C) {
  int wave = (blockIdx.x * blockDim.x + threadIdx.x) >> 6;
  int lane = threadIdx.x & 63;
  const int ntj = N >> 4;
  int mt = wave / ntj, jt = wave - mt * ntj;
  int col = lane & 15, quad = lane >> 4;
  const unsigned int*   ap = A     + (size_t)(mt * 16 + col) * K + quad * 8;
  const unsigned short* bh = BT_hi + (size_t)(jt * 16 + col) * K + quad * 8;
  const unsigned short* bl = BT_lo + (size_t)(jt * 16 + col) * K + quad * 8;
  f32x4 acc = {0.f, 0.f, 0.f, 0.f};
#pragma unroll 4
  for (int kk = 0; kk < K; kk += 32) {
    bf16x8 ahi, alo;
    unpack8v(*(const u32x4*)(ap + kk), *(const u32x4*)(ap + kk + 4), ahi, alo);
    bf16x8 vh = *(const bf16x8*)(bh + kk);
    bf16x8 vl = *(const bf16x8*)(bl + kk);
    acc = __builtin_amdgcn_mfma_f32_16x16x32_bf16(ahi, vh, acc, 0, 0, 0);
    acc = __builtin_amdgcn_mfma_f32_16x16x32_bf16(alo, vh, acc, 0, 0, 0);
    acc = __builtin_amdgcn_mfma_f32_16x16x32_bf16(ahi, vl, acc, 0, 0, 0);
  }
#pragma unroll
  for (int r = 0; r < 4; r++) {
    size_t idx = (size_t)(mt * 16 + quad * 4 + r) * N + jt * 16 + col;
    if (OUTMODE) ((unsigned int*)C)[idx] = packf(fmaxf(acc[r], 0.f));
    else         ((float*)C)[idx] = acc[r];
  }
}

// ---- 16x16 MFMA tile; A = packed u32, NORMAL cached vector loads ----
__device__ __forceinline__ f32x4 mm_tile_n(
    const unsigned int* __restrict__ A, int am0,
    const unsigned short* __restrict__ BH, const unsigned short* __restrict__ BL,
    int bj0, f32x4 acc, int col, int quad) {
  const unsigned int*   ap = A  + (size_t)(am0 + col) * H_ + quad * 8;
  const unsigned short* bh = BH + (size_t)(bj0 + col) * H_ + quad * 8;
  const unsigned short* bl = BL + (size_t)(bj0 + col) * H_ + quad * 8;
#pragma unroll 4
  for (int kk = 0; kk < H_; kk += 32) {
    bf16x8 ahi, alo;
    unpack8v(*(const u32x4*)(ap + kk), *(const u32x4*)(ap + kk + 4), ahi, alo);
    bf16x8 vh = *(const bf16x8*)(bh + kk);
    bf16x8 vl = *(const bf16x8*)(bl + kk);
    acc = __builtin_amdgcn_mfma_f32_16x16x32_bf16(ahi, vh, acc, 0, 0, 0);
    acc = __builtin_amdgcn_mfma_f32_16x16x32_bf16(alo, vh, acc, 0, 0, 0);
    acc = __builtin_amdgcn_mfma_f32_16x16x32_bf16(ahi, vl, acc, 0, 0, 0);
  }
  return acc;
}

// ---------- recurrent: 32 blocks x 32 cols; step-renamed buffers ----------
// hq[t]  : packed h_t       [T][B][H]    written (atomic) stage1, read (normal) stage2
// hc[t]  : packed h_cur     [T+1][B][H]  written (atomic) stage2b, read (normal) next step
// dots[t]: f32              [T][B][T]    atomicAdd partials, read (normal) after sync
// Virgin-address discipline => normal cached reads are always coherent.
__global__ void __launch_bounds__(NTHR) recurrent(
    const unsigned short* __restrict__ WhT_hi, const unsigned short* __restrict__ WhT_lo,
    const unsigned short* __restrict__ WhoT_hi, const unsigned short* __restrict__ WhoT_lo,
    const unsigned short* __restrict__ WoT_hi, const unsigned short* __restrict__ WoT_lo,
    const float* __restrict__ ZC,
    unsigned int* __restrict__ hq,
    unsigned int* __restrict__ hc,
    unsigned int* __restrict__ Opub,
    float* __restrict__ hist_loc,     // [NBLK][T][B][NCOL] block-private f32
    float* __restrict__ dots_g,
    const float* __restrict__ par,
    void* __restrict__ y_out,
    int* __restrict__ cnt,
    const int* __restrict__ flag)
{
  __shared__ float lds_hs[B_][NCOL + 1];
  __shared__ float lds_dt[B_][T_];
  __shared__ float lds_mu[NCOL], lds_sc[NCOL], lds_bb[NCOL];

  const int tid = threadIdx.x, wg = blockIdx.x;
  const int wv = tid >> 6, lane = tid & 63;
  const int col = lane & 15, quad = lane >> 4;
  const int j0 = wg * NCOL;
  const int bt = wv >> 1, ct = wv & 1;
  const int am0 = bt * 16;
  const int cl0 = ct * 16;
  const int jg0 = j0 + cl0;
  const float lam = par[0], eta = par[1];
  const bool isf32 = flag[0] != 0;
  float* hl = hist_loc + (size_t)wg * (T_ * B_ * NCOL);

  // zero hc[0] own cols (atomic stores -> coherent point) + dots slice
  for (int d = tid; d < B_ * NCOL; d += NTHR) {
    int b = d >> 5, c = d & 31;
    astu(hc + (size_t)b * H_ + j0 + c, 0u);
  }
  for (int i = tid; i < T_ * B_ * T_ / NBLK; i += NTHR)
    astf(dots_g + (size_t)wg * (T_ * B_ * T_ / NBLK) + i, 0.f);
  rendezvous(cnt, 0);

  int slot = 1;
  for (int t = 0; t < T_; ++t) {
    const float* zb = ZC + (size_t)t * B_ * H_;
    const unsigned int* hcur = hc + (size_t)t * B_ * H_;       // virgin normal reads
    unsigned int* hqt = hq + (size_t)t * B_ * H_;
    float* dt = dots_g + (size_t)t * B_ * T_;
    // ---- stage 1: h_t = relu(zc + h_cur @ W_h), own cols ----
    {
      f32x4 acc;
#pragma unroll
      for (int r = 0; r < 4; r++)
        acc[r] = zb[(size_t)(am0 + quad * 4 + r) * H_ + jg0 + col];
      acc = mm_tile_n(hcur, am0, WhT_hi, WhT_lo, jg0, acc, col, quad);
#pragma unroll
      for (int r = 0; r < 4; r++) {
        float v = fmaxf(acc[r], 0.f);
        int m = am0 + quad * 4 + r;
        hl[((size_t)t * B_ + m) * NCOL + cl0 + col] = v;
        astu(hqt + (size_t)m * H_ + jg0 + col, packf(v));
      }
    }
    __syncthreads();
    // ---- partial dots over own cols -> atomicAdd into dots[t] ----
    for (int d = tid; d < B_ * (t + 1); d += NTHR) {
      int b = d / (t + 1), s = d - b * (t + 1);
      const f32x4* p = (const f32x4*)(hl + ((size_t)t * B_ + b) * NCOL);
      const f32x4* q = (const f32x4*)(hl + ((size_t)s * B_ + b) * NCOL);
      float sum = 0.f;
#pragma unroll
      for (int i = 0; i < 8; i++) {
        f32x4 a = p[i], c = q[i];
        sum += a[0] * c[0] + a[1] * c[1] + a[2] * c[2] + a[3] * c[3];
      }
      aaddf(dt + (size_t)b * T_ + s, sum);
    }
    rendezvous(cnt, slot++);
    // ---- dots[t] -> LDS (normal loads, virgin addresses) ----
    for (int d = tid; d < B_ * (t + 1); d += NTHR) {
      int b = d / (t + 1), s = d - b * (t + 1);
      lds_dt[b][s] = dt[(size_t)b * T_ + s];
    }
    // ---- hs GEMM tile: h_t @ W_h + zc (h_t via normal loads) ----
    {
      f32x4 acc;
#pragma unroll
      for (int r = 0; r < 4; r++)
        acc[r] = zb[(size_t)(am0 + quad * 4 + r) * H_ + jg0 + col];
      acc = mm_tile_n(hqt, am0, WhT_hi, WhT_lo, jg0, acc, col, quad);
#pragma unroll
      for (int r = 0; r < 4; r++) lds_hs[am0 + quad * 4 + r][cl0 + col] = acc[r];
    }
    __syncthreads();
    // ---- attention: += eta * sum_s lam^(t-s) dots[b][s] * hl[s][b][c] ----
    for (int d = tid; d < B_ * NCOL; d += NTHR) {
      int b = d >> 5, c = d & 31;
      float a = 0.f, w = eta;
      const float* hb = hl + (size_t)b * NCOL + c;
      for (int s = t; s >= 0; --s) {
        a += w * lds_dt[b][s] * hb[(size_t)s * B_ * NCOL];
        w *= lam;
      }
      lds_hs[b][c] += a;
    }
    __syncthreads();
    // ---- batch-norm (block-local) ----
    if (tid < NCOL) {
      int c = tid;
      float sum = 0.f;
#pragma unroll
      for (int b = 0; b < B_; b++) sum += lds_hs[b][c];
      float mu = sum * (1.f / B_);
      float sq = 0.f;
#pragma unroll
      for (int b = 0; b < B_; b++) {
        float dd = lds_hs[b][c] - mu;
        sq += dd * dd;
      }
      float sig = sqrtf(sq * (1.f / B_));
      lds_mu[c] = mu;
      lds_sc[c] = par[2 + j0 + c] / sig;
      lds_bb[c] = par[2 + H_ + j0 + c];
    }
    __syncthreads();
    // ---- apply + publish hc[t+1] own cols ----
    for (int d = tid; d < B_ * NCOL; d += NTHR) {
      int b = d >> 5, c = d & 31;
      float v = (lds_hs[b][c] - lds_mu[c]) * lds_sc[c] + lds_bb[c];
      astu(hc + (size_t)(t + 1) * B_ * H_ + (size_t)b * H_ + j0 + c, packf(fmaxf(v, 0.f)));
    }
    rendezvous(cnt, slot++);
  }
  // ---- o = relu(hc[T] @ W_ho), own cols ----
  {
    const unsigned int* hfin = hc + (size_t)T_ * B_ * H_;
    f32x4 acc = {0.f, 0.f, 0.f, 0.f};
    acc = mm_tile_n(hfin, am0, WhoT_hi, WhoT_lo, jg0, acc, col, quad);
#pragma unroll
    for (int r = 0; r < 4; r++)
      astu(Opub + (size_t)(am0 + quad * 4 + r) * H_ + jg0 + col, packf(fmaxf(acc[r], 0.f)));
  }
  rendezvous(cnt, slot++);
  // ---- y = relu(o @ W_o): 32 tiles on blocks 0..7 (normal loads of Opub) ----
  if (wg < 8) {
    int id = wg * 4 + wv;             // 0..31
    int bt2 = id & 1, jt2 = id >> 1;  // jt2 0..15
    f32x4 acc = {0.f, 0.f, 0.f, 0.f};
    acc = mm_tile_n(Opub, bt2 * 16, WoT_hi, WoT_lo, jt2 * 16, acc, col, quad);
#pragma unroll
    for (int r = 0; r < 4; r++) {
      float v = fmaxf(acc[r], 0.f);
      size_t idx = (size_t)(bt2 * 16 + quad * 4 + r) * NOUT_ + jt2 * 16 + col;
      if (isf32) ((float*)y_out)[idx] = v;
      else       ((unsigned short*)y_out)[idx] = f2bf(v);
    }
  }
}

extern "C" void kernel_launch(void* const* d_in, const int* in_sizes, int n_in,
                              void* d_out, int out_size, void* d_ws, size_t ws_size,
                              hipStream_t stream) {
  const void* x_in = d_in[0];
  const void* W_i  = d_in[1];
  const void* W_z  = d_in[2];
  const void* W_c  = d_in[3];
  const void* W_h  = d_in[4];
  const void* W_ho = d_in[5];
  const void* W_o  = d_in[6];
  const void* lam  = d_in[7];
  const void* eta  = d_in[8];
  const void* g    = d_in[9];
  const void* bb   = d_in[10];

  char* wsp = (char*)d_ws;
  size_t off = 0;
  auto alloc = [&](size_t bytes) {
    void* p = wsp + off;
    off += (bytes + 255) & ~(size_t)255;
    return p;
  };
  int*            flag    = (int*)alloc(16);
  int*            cnt     = (int*)alloc(NSLOT * 4);
  float*          par     = (float*)alloc((2 + 2 * H_) * 4);
  unsigned int*   X_pk    = (unsigned int*)alloc((size_t)T_ * B_ * NIN_ * 4);
  unsigned short* WiT_hi  = (unsigned short*)alloc((size_t)NIN_ * H_ * 2);
  unsigned short* WiT_lo  = (unsigned short*)alloc((size_t)NIN_ * H_ * 2);
  unsigned short* WzT_hi  = (unsigned short*)alloc((size_t)H_ * H_ * 2);
  unsigned short* WzT_lo  = (unsigned short*)alloc((size_t)H_ * H_ * 2);
  unsigned short* WcT_hi  = (unsigned short*)alloc((size_t)H_ * H_ * 2);
  unsigned short* WcT_lo  = (unsigned short*)alloc((size_t)H_ * H_ * 2);
  unsigned short* WhT_hi  = (unsigned short*)alloc((size_t)H_ * H_ * 2);
  unsigned short* WhT_lo  = (unsigned short*)alloc((size_t)H_ * H_ * 2);
  unsigned short* WhoT_hi = (unsigned short*)alloc((size_t)H_ * H_ * 2);
  unsigned short* WhoT_lo = (unsigned short*)alloc((size_t)H_ * H_ * 2);
  unsigned short* WoT_hi  = (unsigned short*)alloc((size_t)H_ * NOUT_ * 2);
  unsigned short* WoT_lo  = (unsigned short*)alloc((size_t)H_ * NOUT_ * 2);
  unsigned int*   S_pk    = (unsigned int*)alloc((size_t)T_ * B_ * H_ * 4);
  unsigned int*   Z_pk    = (unsigned int*)alloc((size_t)T_ * B_ * H_ * 4);
  float*          ZC      = (float*)alloc((size_t)T_ * B_ * H_ * 4);
  unsigned int*   hq      = (unsigned int*)alloc((size_t)T_ * B_ * H_ * 4);
  unsigned int*   hc      = (unsigned int*)alloc((size_t)(T_ + 1) * B_ * H_ * 4);
  unsigned int*   Opub    = (unsigned int*)alloc((size_t)B_ * H_ * 4);
  float*          histloc = (float*)alloc((size_t)NBLK * T_ * B_ * NCOL * 4);
  float*          dots_g  = (float*)alloc((size_t)T_ * B_ * T_ * 4);
  (void)ws_size; (void)in_sizes; (void)n_in; (void)out_size;

  // 1. detect dtype + zero counters; x -> relu+pack; params
  init_detect<<<1, 256, 0, stream>>>((const unsigned short*)x_in, flag, cnt);
  pack_relu_x<<<256, 256, 0, stream>>>(x_in, X_pk, T_ * B_ * NIN_, flag);
  prep_params<<<4, 256, 0, stream>>>(lam, eta, g, bb, par, flag);

  // 2. transpose + hi/lo split weights -> bf16 [N][K]
  split_transpose<<<dim3(H_ / 32, NIN_ / 32), 256, 0, stream>>>(W_i, WiT_hi, WiT_lo, NIN_, H_, flag);
  split_transpose<<<dim3(H_ / 32, H_ / 32), 256, 0, stream>>>(W_z, WzT_hi, WzT_lo, H_, H_, flag);
  split_transpose<<<dim3(H_ / 32, H_ / 32), 256, 0, stream>>>(W_c, WcT_hi, WcT_lo, H_, H_, flag);
  split_transpose<<<dim3(H_ / 32, H_ / 32), 256, 0, stream>>>(W_h, WhT_hi, WhT_lo, H_, H_, flag);
  split_transpose<<<dim3(H_ / 32, H_ / 32), 256, 0, stream>>>(W_ho, WhoT_hi, WhoT_lo, H_, H_, flag);
  split_transpose<<<dim3(NOUT_ / 32, H_ / 32), 256, 0, stream>>>(W_o, WoT_hi, WoT_lo, H_, NOUT_, flag);

  // 3. phase A (packed): S = relu(X@W_i); Z = relu(S@W_z); ZC = Z@W_c (f32)
  gemmA_pk<NIN_, H_, 1><<<1024, 256, 0, stream>>>(X_pk, WiT_hi, WiT_lo, S_pk);
  gemmA_pk<H_,   H_, 1><<<1024, 256, 0, stream>>>(S_pk, WzT_hi, WzT_lo, Z_pk);
  gemmA_pk<H_,   H_, 0><<<1024, 256, 0, stream>>>(Z_pk, WcT_hi, WcT_lo, ZC);

  // 4. phase B: recurrence + readout, step-renamed buffers + normal cached reads
  recurrent<<<NBLK, NTHR, 0, stream>>>(WhT_hi, WhT_lo, WhoT_hi, WhoT_lo, WoT_hi, WoT_lo,
                                       ZC, hq, hc, Opub, histloc, dots_g,
                                       par, d_out, cnt, flag);
}

// Round 10
// 1679.029 us; speedup vs baseline: 2.1072x; 1.1317x over previous
//
#include <hip/hip_runtime.h>
#include <hip/hip_bf16.h>

#define T_   32
#define B_   32
#define NIN_ 512
#define H_   1024
#define NOUT_ 256
#define NBLK 32
#define NTHR 256
#define NCOL 32
#define NSLOT 80

typedef short bf16x8 __attribute__((ext_vector_type(8)));
typedef float f32x4  __attribute__((ext_vector_type(4)));
typedef unsigned int u32x4 __attribute__((ext_vector_type(4)));

__device__ __forceinline__ float bf2f(unsigned short u) {
  union { unsigned int i; float f; } x; x.i = ((unsigned int)u) << 16; return x.f;
}
__device__ __forceinline__ unsigned short f2bf(float f) {
  __hip_bfloat16 h = __float2bfloat16(f);
  return *reinterpret_cast<unsigned short*>(&h);
}
// pack f32 -> (bf16_hi << 16) | bf16_lo
__device__ __forceinline__ unsigned int packf(float v) {
  unsigned short h = f2bf(v);
  unsigned short l = f2bf(v - bf2f(h));
  return ((unsigned int)h << 16) | l;
}
// 8 packed u32 (two u32x4) -> hi/lo bf16x8
__device__ __forceinline__ void unpack8v(u32x4 a, u32x4 b, bf16x8& hi, bf16x8& lo) {
  unsigned int t[8] = {a[0], a[1], a[2], a[3], b[0], b[1], b[2], b[3]};
  union { bf16x8 v; unsigned int u[4]; } H, L;
#pragma unroll
  for (int j = 0; j < 4; j++) {
    unsigned int e = t[2 * j], o = t[2 * j + 1];
    H.u[j] = (o & 0xFFFF0000u) | (e >> 16);
    L.u[j] = (o << 16) | (e & 0xFFFFu);
  }
  hi = H.v; lo = L.v;
}

// ---- publish primitives: relaxed agent-scope atomics (write-through, no L2 dirty) ----
__device__ __forceinline__ void astu(unsigned int* p, unsigned int v) {
  __hip_atomic_store(p, v, __ATOMIC_RELAXED, __HIP_MEMORY_SCOPE_AGENT);
}
__device__ __forceinline__ void astf(float* p, float v) {
  __hip_atomic_store(p, v, __ATOMIC_RELAXED, __HIP_MEMORY_SCOPE_AGENT);
}
__device__ __forceinline__ void aaddf(float* p, float v) {
  __hip_atomic_fetch_add(p, v, __ATOMIC_RELAXED, __HIP_MEMORY_SCOPE_AGENT);
}

// ---- rendezvous: fresh slot; release add, relaxed spin (no L2 invalidate) ----
__device__ __forceinline__ void rendezvous(int* cnt, int slot) {
  __syncthreads();
  if (threadIdx.x == 0) {
    __hip_atomic_fetch_add(&cnt[slot], 1, __ATOMIC_RELEASE, __HIP_MEMORY_SCOPE_AGENT);
    while (__hip_atomic_load(&cnt[slot], __ATOMIC_RELAXED, __HIP_MEMORY_SCOPE_AGENT) < NBLK)
      __builtin_amdgcn_s_sleep(1);
    __atomic_signal_fence(__ATOMIC_ACQUIRE);
  }
  __syncthreads();
}

// ---------- dtype detect + counter init ----------
__global__ void init_detect(const unsigned short* __restrict__ x_raw,
                            int* __restrict__ flag, int* __restrict__ cnt) {
  __shared__ int bad;
  if (threadIdx.x == 0) bad = 0;
  __syncthreads();
  int c = 0;
  for (int i = threadIdx.x; i < 2048; i += 256) {
    float v = bf2f(x_raw[i]);
    if (!(fabsf(v) < 1e9f)) c++;
  }
  if (c) atomicAdd(&bad, 1);
  __syncthreads();
  if (threadIdx.x == 0) flag[0] = bad ? 1 : 0;  // 1 = inputs are f32
  for (int i = threadIdx.x; i < NSLOT; i += 256)
    __hip_atomic_store(&cnt[i], 0, __ATOMIC_RELAXED, __HIP_MEMORY_SCOPE_AGENT);
}

// ---------- x -> relu + pack ----------
__global__ void pack_relu_x(const void* __restrict__ src, unsigned int* __restrict__ dst,
                            int n, const int* __restrict__ flag) {
  bool isf32 = flag[0] != 0;
  for (int i = blockIdx.x * 256 + threadIdx.x; i < n; i += gridDim.x * 256) {
    float v = isf32 ? ((const float*)src)[i] : bf2f(((const unsigned short*)src)[i]);
    dst[i] = packf(fmaxf(v, 0.f));
  }
}

// ---------- params -> float: [lam, eta, g[1024], b[1024]] ----------
__global__ void prep_params(const void* lam, const void* eta, const void* g, const void* b,
                            float* __restrict__ par, const int* __restrict__ flag) {
  bool isf32 = flag[0] != 0;
  int t = blockIdx.x * 256 + threadIdx.x;
  if (t == 0) {
    par[0] = isf32 ? ((const float*)lam)[0] : bf2f(((const unsigned short*)lam)[0]);
    par[1] = isf32 ? ((const float*)eta)[0] : bf2f(((const unsigned short*)eta)[0]);
  }
  if (t < H_) {
    par[2 + t]      = isf32 ? ((const float*)g)[t] : bf2f(((const unsigned short*)g)[t]);
    par[2 + H_ + t] = isf32 ? ((const float*)b)[t] : bf2f(((const unsigned short*)b)[t]);
  }
}

// ---------- transpose + hi/lo split: W [R][C] -> bf16 [C][R] ----------
__global__ void split_transpose(const void* __restrict__ in,
                                unsigned short* __restrict__ out_hi,
                                unsigned short* __restrict__ out_lo,
                                int R, int C, const int* __restrict__ flag) {
  __shared__ unsigned short thi[32][33], tlo[32][33];
  bool isf32 = flag[0] != 0;
  int c0 = blockIdx.x * 32, r0 = blockIdx.y * 32;
  int tx = threadIdx.x & 31, ty = threadIdx.x >> 5;
  for (int i = ty; i < 32; i += 8) {
    size_t idx = (size_t)(r0 + i) * C + c0 + tx;
    float v = isf32 ? ((const float*)in)[idx] : bf2f(((const unsigned short*)in)[idx]);
    unsigned short h = f2bf(v);
    thi[i][tx] = h;
    tlo[i][tx] = f2bf(v - bf2f(h));
  }
  __syncthreads();
  for (int i = ty; i < 32; i += 8) {
    out_hi[(size_t)(c0 + i) * R + r0 + tx] = thi[tx][i];
    out_lo[(size_t)(c0 + i) * R + r0 + tx] = tlo[tx][i];
  }
}

// ---------- phase-A GEMM on packed A: out = relu+pack (1) or f32 (0) ----------
template<int K, int N, int OUTMODE>
__global__ void gemmA_pk(const unsigned int* __restrict__ A,
                         const unsigned short* __restrict__ BT_hi,
                         const unsigned short* __restrict__ BT_lo,
                         void* __restrict__ C) {
  int wave = (blockIdx.x * blockDim.x + threadIdx.x) >> 6;
  int lane = threadIdx.x & 63;
  const int ntj = N >> 4;
  int mt = wave / ntj, jt = wave - mt * ntj;
  int col = lane & 15, quad = lane >> 4;
  const unsigned int*   ap = A     + (size_t)(mt * 16 + col) * K + quad * 8;
  const unsigned short* bh = BT_hi + (size_t)(jt * 16 + col) * K + quad * 8;
  const unsigned short* bl = BT_lo + (size_t)(jt * 16 + col) * K + quad * 8;
  f32x4 acc = {0.f, 0.f, 0.f, 0.f};
#pragma unroll 4
  for (int kk = 0; kk < K; kk += 32) {
    bf16x8 ahi, alo;
    unpack8v(*(const u32x4*)(ap + kk), *(const u32x4*)(ap + kk + 4), ahi, alo);
    bf16x8 vh = *(const bf16x8*)(bh + kk);
    bf16x8 vl = *(const bf16x8*)(bl + kk);
    acc = __builtin_amdgcn_mfma_f32_16x16x32_bf16(ahi, vh, acc, 0, 0, 0);
    acc = __builtin_amdgcn_mfma_f32_16x16x32_bf16(alo, vh, acc, 0, 0, 0);
    acc = __builtin_amdgcn_mfma_f32_16x16x32_bf16(ahi, vl, acc, 0, 0, 0);
  }
#pragma unroll
  for (int r = 0; r < 4; r++) {
    size_t idx = (size_t)(mt * 16 + quad * 4 + r) * N + jt * 16 + col;
    if (OUTMODE) ((unsigned int*)C)[idx] = packf(fmaxf(acc[r], 0.f));
    else         ((float*)C)[idx] = acc[r];
  }
}

// ---- 16x16 MFMA tile; A = packed u32, chunked 16-load prefetch (hide L3 latency) ----
__device__ __forceinline__ f32x4 mm_tile_pf(
    const unsigned int* __restrict__ A, int am0,
    const unsigned short* __restrict__ BH, const unsigned short* __restrict__ BL,
    int bj0, f32x4 acc, int col, int quad) {
  const unsigned int*   ap = A  + (size_t)(am0 + col) * H_ + quad * 8;
  const unsigned short* bh = BH + (size_t)(bj0 + col) * H_ + quad * 8;
  const unsigned short* bl = BL + (size_t)(bj0 + col) * H_ + quad * 8;
#pragma unroll 1
  for (int kk = 0; kk < H_; kk += 256) {
    u32x4 ab[16];
    // issue all 16 A-loads back-to-back (graded vmcnt keeps them in flight)
#pragma unroll
    for (int i = 0; i < 8; i++) {
      ab[2 * i]     = *(const u32x4*)(ap + kk + 32 * i);
      ab[2 * i + 1] = *(const u32x4*)(ap + kk + 32 * i + 4);
    }
#pragma unroll
    for (int i = 0; i < 8; i++) {
      bf16x8 ahi, alo;
      unpack8v(ab[2 * i], ab[2 * i + 1], ahi, alo);
      bf16x8 vh = *(const bf16x8*)(bh + kk + 32 * i);
      bf16x8 vl = *(const bf16x8*)(bl + kk + 32 * i);
      acc = __builtin_amdgcn_mfma_f32_16x16x32_bf16(ahi, vh, acc, 0, 0, 0);
      acc = __builtin_amdgcn_mfma_f32_16x16x32_bf16(alo, vh, acc, 0, 0, 0);
      acc = __builtin_amdgcn_mfma_f32_16x16x32_bf16(ahi, vl, acc, 0, 0, 0);
    }
  }
  return acc;
}

// ---------- recurrent: 32 blocks x 32 cols; step-renamed buffers ----------
__global__ void __launch_bounds__(NTHR) recurrent(
    const unsigned short* __restrict__ WhT_hi, const unsigned short* __restrict__ WhT_lo,
    const unsigned short* __restrict__ WhoT_hi, const unsigned short* __restrict__ WhoT_lo,
    const unsigned short* __restrict__ WoT_hi, const unsigned short* __restrict__ WoT_lo,
    const float* __restrict__ ZC,
    unsigned int* __restrict__ hq,
    unsigned int* __restrict__ hc,
    unsigned int* __restrict__ Opub,
    float* __restrict__ hist_loc,     // [NBLK][T][B][NCOL] block-private f32
    float* __restrict__ dots_g,
    const float* __restrict__ par,
    void* __restrict__ y_out,
    int* __restrict__ cnt,
    const int* __restrict__ flag)
{
  __shared__ float lds_hs[B_][NCOL + 1];
  __shared__ float lds_dt[B_][T_];
  __shared__ float lds_mu[NCOL], lds_sc[NCOL], lds_bb[NCOL];

  const int tid = threadIdx.x, wg = blockIdx.x;
  const int wv = tid >> 6, lane = tid & 63;
  const int col = lane & 15, quad = lane >> 4;
  const int j0 = wg * NCOL;
  const int bt = wv >> 1, ct = wv & 1;
  const int am0 = bt * 16;
  const int cl0 = ct * 16;
  const int jg0 = j0 + cl0;
  const float lam = par[0], eta = par[1];
  const bool isf32 = flag[0] != 0;
  float* hl = hist_loc + (size_t)wg * (T_ * B_ * NCOL);

  // zero hc[0] own cols + dots slice
  for (int d = tid; d < B_ * NCOL; d += NTHR) {
    int b = d >> 5, c = d & 31;
    astu(hc + (size_t)b * H_ + j0 + c, 0u);
  }
  for (int i = tid; i < T_ * B_ * T_ / NBLK; i += NTHR)
    astf(dots_g + (size_t)wg * (T_ * B_ * T_ / NBLK) + i, 0.f);
  rendezvous(cnt, 0);

  int slot = 1;
  for (int t = 0; t < T_; ++t) {
    const float* zb = ZC + (size_t)t * B_ * H_;
    const unsigned int* hcur = hc + (size_t)t * B_ * H_;       // virgin normal reads
    unsigned int* hqt = hq + (size_t)t * B_ * H_;
    float* dt = dots_g + (size_t)t * B_ * T_;
    // ---- stage 1: h_t = relu(zc + h_cur @ W_h), own cols ----
    {
      f32x4 acc;
#pragma unroll
      for (int r = 0; r < 4; r++)
        acc[r] = zb[(size_t)(am0 + quad * 4 + r) * H_ + jg0 + col];
      acc = mm_tile_pf(hcur, am0, WhT_hi, WhT_lo, jg0, acc, col, quad);
#pragma unroll
      for (int r = 0; r < 4; r++) {
        float v = fmaxf(acc[r], 0.f);
        int m = am0 + quad * 4 + r;
        hl[((size_t)t * B_ + m) * NCOL + cl0 + col] = v;
        astu(hqt + (size_t)m * H_ + jg0 + col, packf(v));
      }
    }
    __syncthreads();
    // ---- partial dots over own cols -> atomicAdd (batch rotated by wg to de-conflict) ----
    for (int d = tid; d < B_ * (t + 1); d += NTHR) {
      int b = ((d / (t + 1)) + wg) & (B_ - 1);
      int s = d % (t + 1);
      const f32x4* p = (const f32x4*)(hl + ((size_t)t * B_ + b) * NCOL);
      const f32x4* q = (const f32x4*)(hl + ((size_t)s * B_ + b) * NCOL);
      float sum = 0.f;
#pragma unroll
      for (int i = 0; i < 8; i++) {
        f32x4 a = p[i], c = q[i];
        sum += a[0] * c[0] + a[1] * c[1] + a[2] * c[2] + a[3] * c[3];
      }
      aaddf(dt + (size_t)b * T_ + s, sum);
    }
    rendezvous(cnt, slot++);
    // ---- dots[t] -> LDS (normal loads, virgin addresses) ----
    for (int d = tid; d < B_ * (t + 1); d += NTHR) {
      int b = d / (t + 1), s = d - b * (t + 1);
      lds_dt[b][s] = dt[(size_t)b * T_ + s];
    }
    // ---- hs GEMM tile: h_t @ W_h + zc (h_t via normal loads) ----
    {
      f32x4 acc;
#pragma unroll
      for (int r = 0; r < 4; r++)
        acc[r] = zb[(size_t)(am0 + quad * 4 + r) * H_ + jg0 + col];
      acc = mm_tile_pf(hqt, am0, WhT_hi, WhT_lo, jg0, acc, col, quad);
#pragma unroll
      for (int r = 0; r < 4; r++) lds_hs[am0 + quad * 4 + r][cl0 + col] = acc[r];
    }
    __syncthreads();
    // ---- attention: += eta * sum_s lam^(t-s) dots[b][s] * hl[s][b][c] ----
    for (int d = tid; d < B_ * NCOL; d += NTHR) {
      int b = d >> 5, c = d & 31;
      float a = 0.f, w = eta;
      const float* hb = hl + (size_t)b * NCOL + c;
      for (int s = t; s >= 0; --s) {
        a += w * lds_dt[b][s] * hb[(size_t)s * B_ * NCOL];
        w *= lam;
      }
      lds_hs[b][c] += a;
    }
    __syncthreads();
    // ---- batch-norm (block-local) ----
    if (tid < NCOL) {
      int c = tid;
      float sum = 0.f;
#pragma unroll
      for (int b = 0; b < B_; b++) sum += lds_hs[b][c];
      float mu = sum * (1.f / B_);
      float sq = 0.f;
#pragma unroll
      for (int b = 0; b < B_; b++) {
        float dd = lds_hs[b][c] - mu;
        sq += dd * dd;
      }
      float sig = sqrtf(sq * (1.f / B_));
      lds_mu[c] = mu;
      lds_sc[c] = par[2 + j0 + c] / sig;
      lds_bb[c] = par[2 + H_ + j0 + c];
    }
    __syncthreads();
    // ---- apply + publish hc[t+1] own cols ----
    for (int d = tid; d < B_ * NCOL; d += NTHR) {
      int b = d >> 5, c = d & 31;
      float v = (lds_hs[b][c] - lds_mu[c]) * lds_sc[c] + lds_bb[c];
      astu(hc + (size_t)(t + 1) * B_ * H_ + (size_t)b * H_ + j0 + c, packf(fmaxf(v, 0.f)));
    }
    rendezvous(cnt, slot++);
  }
  // ---- o = relu(hc[T] @ W_ho), own cols ----
  {
    const unsigned int* hfin = hc + (size_t)T_ * B_ * H_;
    f32x4 acc = {0.f, 0.f, 0.f, 0.f};
    acc = mm_tile_pf(hfin, am0, WhoT_hi, WhoT_lo, jg0, acc, col, quad);
#pragma unroll
    for (int r = 0; r < 4; r++)
      astu(Opub + (size_t)(am0 + quad * 4 + r) * H_ + jg0 + col, packf(fmaxf(acc[r], 0.f)));
  }
  rendezvous(cnt, slot++);
  // ---- y = relu(o @ W_o): 32 tiles on blocks 0..7 (normal loads of Opub) ----
  if (wg < 8) {
    int id = wg * 4 + wv;             // 0..31
    int bt2 = id & 1, jt2 = id >> 1;  // jt2 0..15
    f32x4 acc = {0.f, 0.f, 0.f, 0.f};
    acc = mm_tile_pf(Opub, bt2 * 16, WoT_hi, WoT_lo, jt2 * 16, acc, col, quad);
#pragma unroll
    for (int r = 0; r < 4; r++) {
      float v = fmaxf(acc[r], 0.f);
      size_t idx = (size_t)(bt2 * 16 + quad * 4 + r) * NOUT_ + jt2 * 16 + col;
      if (isf32) ((float*)y_out)[idx] = v;
      else       ((unsigned short*)y_out)[idx] = f2bf(v);
    }
  }
}

extern "C" void kernel_launch(void* const* d_in, const int* in_sizes, int n_in,
                              void* d_out, int out_size, void* d_ws, size_t ws_size,
                              hipStream_t stream) {
  const void* x_in = d_in[0];
  const void* W_i  = d_in[1];
  const void* W_z  = d_in[2];
  const void* W_c  = d_in[3];
  const void* W_h  = d_in[4];
  const void* W_ho = d_in[5];
  const void* W_o  = d_in[6];
  const void* lam  = d_in[7];
  const void* eta  = d_in[8];
  const void* g    = d_in[9];
  const void* bb   = d_in[10];

  char* wsp = (char*)d_ws;
  size_t off = 0;
  auto alloc = [&](size_t bytes) {
    void* p = wsp + off;
    off += (bytes + 255) & ~(size_t)255;
    return p;
  };
  int*            flag    = (int*)alloc(16);
  int*            cnt     = (int*)alloc(NSLOT * 4);
  float*          par     = (float*)alloc((2 + 2 * H_) * 4);
  unsigned int*   X_pk    = (unsigned int*)alloc((size_t)T_ * B_ * NIN_ * 4);
  unsigned short* WiT_hi  = (unsigned short*)alloc((size_t)NIN_ * H_ * 2);
  unsigned short* WiT_lo  = (unsigned short*)alloc((size_t)NIN_ * H_ * 2);
  unsigned short* WzT_hi  = (unsigned short*)alloc((size_t)H_ * H_ * 2);
  unsigned short* WzT_lo  = (unsigned short*)alloc((size_t)H_ * H_ * 2);
  unsigned short* WcT_hi  = (unsigned short*)alloc((size_t)H_ * H_ * 2);
  unsigned short* WcT_lo  = (unsigned short*)alloc((size_t)H_ * H_ * 2);
  unsigned short* WhT_hi  = (unsigned short*)alloc((size_t)H_ * H_ * 2);
  unsigned short* WhT_lo  = (unsigned short*)alloc((size_t)H_ * H_ * 2);
  unsigned short* WhoT_hi = (unsigned short*)alloc((size_t)H_ * H_ * 2);
  unsigned short* WhoT_lo = (unsigned short*)alloc((size_t)H_ * H_ * 2);
  unsigned short* WoT_hi  = (unsigned short*)alloc((size_t)H_ * NOUT_ * 2);
  unsigned short* WoT_lo  = (unsigned short*)alloc((size_t)H_ * NOUT_ * 2);
  unsigned int*   S_pk    = (unsigned int*)alloc((size_t)T_ * B_ * H_ * 4);
  unsigned int*   Z_pk    = (unsigned int*)alloc((size_t)T_ * B_ * H_ * 4);
  float*          ZC      = (float*)alloc((size_t)T_ * B_ * H_ * 4);
  unsigned int*   hq      = (unsigned int*)alloc((size_t)T_ * B_ * H_ * 4);
  unsigned int*   hc      = (unsigned int*)alloc((size_t)(T_ + 1) * B_ * H_ * 4);
  unsigned int*   Opub    = (unsigned int*)alloc((size_t)B_ * H_ * 4);
  float*          histloc = (float*)alloc((size_t)NBLK * T_ * B_ * NCOL * 4);
  float*          dots_g  = (float*)alloc((size_t)T_ * B_ * T_ * 4);
  (void)ws_size; (void)in_sizes; (void)n_in; (void)out_size;

  // 1. detect dtype + zero counters; x -> relu+pack; params
  init_detect<<<1, 256, 0, stream>>>((const unsigned short*)x_in, flag, cnt);
  pack_relu_x<<<256, 256, 0, stream>>>(x_in, X_pk, T_ * B_ * NIN_, flag);
  prep_params<<<4, 256, 0, stream>>>(lam, eta, g, bb, par, flag);

  // 2. transpose + hi/lo split weights -> bf16 [N][K]
  split_transpose<<<dim3(H_ / 32, NIN_ / 32), 256, 0, stream>>>(W_i, WiT_hi, WiT_lo, NIN_, H_, flag);
  split_transpose<<<dim3(H_ / 32, H_ / 32), 256, 0, stream>>>(W_z, WzT_hi, WzT_lo, H_, H_, flag);
  split_transpose<<<dim3(H_ / 32, H_ / 32), 256, 0, stream>>>(W_c, WcT_hi, WcT_lo, H_, H_, flag);
  split_transpose<<<dim3(H_ / 32, H_ / 32), 256, 0, stream>>>(W_h, WhT_hi, WhT_lo, H_, H_, flag);
  split_transpose<<<dim3(H_ / 32, H_ / 32), 256, 0, stream>>>(W_ho, WhoT_hi, WhoT_lo, H_, H_, flag);
  split_transpose<<<dim3(NOUT_ / 32, H_ / 32), 256, 0, stream>>>(W_o, WoT_hi, WoT_lo, H_, NOUT_, flag);

  // 3. phase A (packed): S = relu(X@W_i); Z = relu(S@W_z); ZC = Z@W_c (f32)
  gemmA_pk<NIN_, H_, 1><<<1024, 256, 0, stream>>>(X_pk, WiT_hi, WiT_lo, S_pk);
  gemmA_pk<H_,   H_, 1><<<1024, 256, 0, stream>>>(S_pk, WzT_hi, WzT_lo, Z_pk);
  gemmA_pk<H_,   H_, 0><<<1024, 256, 0, stream>>>(Z_pk, WcT_hi, WcT_lo, ZC);

  // 4. phase B: recurrence + readout, step-renamed buffers + prefetched GEMM tiles
  recurrent<<<NBLK, NTHR, 0, stream>>>(WhT_hi, WhT_lo, WhoT_hi, WhoT_lo, WoT_hi, WoT_lo,
                                       ZC, hq, hc, Opub, histloc, dots_g,
                                       par, d_out, cnt, flag);
}

// Round 11
// 1646.971 us; speedup vs baseline: 2.1482x; 1.0195x over previous
//
#include <hip/hip_runtime.h>
#include <hip/hip_bf16.h>

#define T_   32
#define B_   32
#define NIN_ 512
#define H_   1024
#define NOUT_ 256
#define NBLK 32
#define NTHR 256
#define NCOL 32
#define NSLOT 80

typedef short bf16x8 __attribute__((ext_vector_type(8)));
typedef float f32x4  __attribute__((ext_vector_type(4)));
typedef unsigned int u32x4 __attribute__((ext_vector_type(4)));

__device__ __forceinline__ float bf2f(unsigned short u) {
  union { unsigned int i; float f; } x; x.i = ((unsigned int)u) << 16; return x.f;
}
__device__ __forceinline__ unsigned short f2bf(float f) {
  __hip_bfloat16 h = __float2bfloat16(f);
  return *reinterpret_cast<unsigned short*>(&h);
}
// pack f32 -> (bf16_hi << 16) | bf16_lo
__device__ __forceinline__ unsigned int packf(float v) {
  unsigned short h = f2bf(v);
  unsigned short l = f2bf(v - bf2f(h));
  return ((unsigned int)h << 16) | l;
}
// 8 packed u32 (two u32x4) -> hi/lo bf16x8
__device__ __forceinline__ void unpack8v(u32x4 a, u32x4 b, bf16x8& hi, bf16x8& lo) {
  unsigned int t[8] = {a[0], a[1], a[2], a[3], b[0], b[1], b[2], b[3]};
  union { bf16x8 v; unsigned int u[4]; } H, L;
#pragma unroll
  for (int j = 0; j < 4; j++) {
    unsigned int e = t[2 * j], o = t[2 * j + 1];
    H.u[j] = (o & 0xFFFF0000u) | (e >> 16);
    L.u[j] = (o << 16) | (e & 0xFFFFu);
  }
  hi = H.v; lo = L.v;
}

// ---- publish primitives: relaxed agent-scope atomics (write-through to L3, no L2 dirty) ----
__device__ __forceinline__ void astu(unsigned int* p, unsigned int v) {
  __hip_atomic_store(p, v, __ATOMIC_RELAXED, __HIP_MEMORY_SCOPE_AGENT);
}
__device__ __forceinline__ void astf(float* p, float v) {
  __hip_atomic_store(p, v, __ATOMIC_RELAXED, __HIP_MEMORY_SCOPE_AGENT);
}
__device__ __forceinline__ void aaddf(float* p, float v) {
  __hip_atomic_fetch_add(p, v, __ATOMIC_RELAXED, __HIP_MEMORY_SCOPE_AGENT);
}

// ---- rendezvous: fully RELAXED arrival (data already drained to L3 by the
// vmcnt(0) the compiler emits for __syncthreads; a RELEASE here would compile
// to an agent-scope L2 writeback walk on gfx950 — the suspected 20 us/sync) ----
__device__ __forceinline__ void rendezvous(int* cnt, int slot) {
  __syncthreads();
  if (threadIdx.x == 0) {
    __hip_atomic_fetch_add(&cnt[slot], 1, __ATOMIC_RELAXED, __HIP_MEMORY_SCOPE_AGENT);
    while (__hip_atomic_load(&cnt[slot], __ATOMIC_RELAXED, __HIP_MEMORY_SCOPE_AGENT) < NBLK)
      __builtin_amdgcn_s_sleep(1);
    __atomic_signal_fence(__ATOMIC_ACQUIRE);
  }
  __syncthreads();
}

// ---------- dtype detect + counter init ----------
__global__ void init_detect(const unsigned short* __restrict__ x_raw,
                            int* __restrict__ flag, int* __restrict__ cnt) {
  __shared__ int bad;
  if (threadIdx.x == 0) bad = 0;
  __syncthreads();
  int c = 0;
  for (int i = threadIdx.x; i < 2048; i += 256) {
    float v = bf2f(x_raw[i]);
    if (!(fabsf(v) < 1e9f)) c++;
  }
  if (c) atomicAdd(&bad, 1);
  __syncthreads();
  if (threadIdx.x == 0) flag[0] = bad ? 1 : 0;  // 1 = inputs are f32
  for (int i = threadIdx.x; i < NSLOT; i += 256)
    __hip_atomic_store(&cnt[i], 0, __ATOMIC_RELAXED, __HIP_MEMORY_SCOPE_AGENT);
}

// ---------- x -> relu + pack ----------
__global__ void pack_relu_x(const void* __restrict__ src, unsigned int* __restrict__ dst,
                            int n, const int* __restrict__ flag) {
  bool isf32 = flag[0] != 0;
  for (int i = blockIdx.x * 256 + threadIdx.x; i < n; i += gridDim.x * 256) {
    float v = isf32 ? ((const float*)src)[i] : bf2f(((const unsigned short*)src)[i]);
    dst[i] = packf(fmaxf(v, 0.f));
  }
}

// ---------- params -> float: [lam, eta, g[1024], b[1024]] ----------
__global__ void prep_params(const void* lam, const void* eta, const void* g, const void* b,
                            float* __restrict__ par, const int* __restrict__ flag) {
  bool isf32 = flag[0] != 0;
  int t = blockIdx.x * 256 + threadIdx.x;
  if (t == 0) {
    par[0] = isf32 ? ((const float*)lam)[0] : bf2f(((const unsigned short*)lam)[0]);
    par[1] = isf32 ? ((const float*)eta)[0] : bf2f(((const unsigned short*)eta)[0]);
  }
  if (t < H_) {
    par[2 + t]      = isf32 ? ((const float*)g)[t] : bf2f(((const unsigned short*)g)[t]);
    par[2 + H_ + t] = isf32 ? ((const float*)b)[t] : bf2f(((const unsigned short*)b)[t]);
  }
}

// ---------- transpose + hi/lo split: W [R][C] -> bf16 [C][R] ----------
__global__ void split_transpose(const void* __restrict__ in,
                                unsigned short* __restrict__ out_hi,
                                unsigned short* __restrict__ out_lo,
                                int R, int C, const int* __restrict__ flag) {
  __shared__ unsigned short thi[32][33], tlo[32][33];
  bool isf32 = flag[0] != 0;
  int c0 = blockIdx.x * 32, r0 = blockIdx.y * 32;
  int tx = threadIdx.x & 31, ty = threadIdx.x >> 5;
  for (int i = ty; i < 32; i += 8) {
    size_t idx = (size_t)(r0 + i) * C + c0 + tx;
    float v = isf32 ? ((const float*)in)[idx] : bf2f(((const unsigned short*)in)[idx]);
    unsigned short h = f2bf(v);
    thi[i][tx] = h;
    tlo[i][tx] = f2bf(v - bf2f(h));
  }
  __syncthreads();
  for (int i = ty; i < 32; i += 8) {
    out_hi[(size_t)(c0 + i) * R + r0 + tx] = thi[tx][i];
    out_lo[(size_t)(c0 + i) * R + r0 + tx] = tlo[tx][i];
  }
}

// ---------- phase-A GEMM on packed A: out = relu+pack (1) or f32 (0) ----------
template<int K, int N, int OUTMODE>
__global__ void gemmA_pk(const unsigned int* __restrict__ A,
                         const unsigned short* __restrict__ BT_hi,
                         const unsigned short* __restrict__ BT_lo,
                         void* __restrict__ C) {
  int wave = (blockIdx.x * blockDim.x + threadIdx.x) >> 6;
  int lane = threadIdx.x & 63;
  const int ntj = N >> 4;
  int mt = wave / ntj, jt = wave - mt * ntj;
  int col = lane & 15, quad = lane >> 4;
  const unsigned int*   ap = A     + (size_t)(mt * 16 + col) * K + quad * 8;
  const unsigned short* bh = BT_hi + (size_t)(jt * 16 + col) * K + quad * 8;
  const unsigned short* bl = BT_lo + (size_t)(jt * 16 + col) * K + quad * 8;
  f32x4 acc = {0.f, 0.f, 0.f, 0.f};
#pragma unroll 4
  for (int kk = 0; kk < K; kk += 32) {
    bf16x8 ahi, alo;
    unpack8v(*(const u32x4*)(ap + kk), *(const u32x4*)(ap + kk + 4), ahi, alo);
    bf16x8 vh = *(const bf16x8*)(bh + kk);
    bf16x8 vl = *(const bf16x8*)(bl + kk);
    acc = __builtin_amdgcn_mfma_f32_16x16x32_bf16(ahi, vh, acc, 0, 0, 0);
    acc = __builtin_amdgcn_mfma_f32_16x16x32_bf16(alo, vh, acc, 0, 0, 0);
    acc = __builtin_amdgcn_mfma_f32_16x16x32_bf16(ahi, vl, acc, 0, 0, 0);
  }
#pragma unroll
  for (int r = 0; r < 4; r++) {
    size_t idx = (size_t)(mt * 16 + quad * 4 + r) * N + jt * 16 + col;
    if (OUTMODE) ((unsigned int*)C)[idx] = packf(fmaxf(acc[r], 0.f));
    else         ((float*)C)[idx] = acc[r];
  }
}

// ---- 16x16 MFMA tile; A = packed u32, chunked 16-load prefetch (hide L3 latency) ----
__device__ __forceinline__ f32x4 mm_tile_pf(
    const unsigned int* __restrict__ A, int am0,
    const unsigned short* __restrict__ BH, const unsigned short* __restrict__ BL,
    int bj0, f32x4 acc, int col, int quad) {
  const unsigned int*   ap = A  + (size_t)(am0 + col) * H_ + quad * 8;
  const unsigned short* bh = BH + (size_t)(bj0 + col) * H_ + quad * 8;
  const unsigned short* bl = BL + (size_t)(bj0 + col) * H_ + quad * 8;
#pragma unroll 1
  for (int kk = 0; kk < H_; kk += 256) {
    u32x4 ab[16];
#pragma unroll
    for (int i = 0; i < 8; i++) {
      ab[2 * i]     = *(const u32x4*)(ap + kk + 32 * i);
      ab[2 * i + 1] = *(const u32x4*)(ap + kk + 32 * i + 4);
    }
#pragma unroll
    for (int i = 0; i < 8; i++) {
      bf16x8 ahi, alo;
      unpack8v(ab[2 * i], ab[2 * i + 1], ahi, alo);
      bf16x8 vh = *(const bf16x8*)(bh + kk + 32 * i);
      bf16x8 vl = *(const bf16x8*)(bl + kk + 32 * i);
      acc = __builtin_amdgcn_mfma_f32_16x16x32_bf16(ahi, vh, acc, 0, 0, 0);
      acc = __builtin_amdgcn_mfma_f32_16x16x32_bf16(alo, vh, acc, 0, 0, 0);
      acc = __builtin_amdgcn_mfma_f32_16x16x32_bf16(ahi, vl, acc, 0, 0, 0);
    }
  }
  return acc;
}

// ---------- recurrent: 32 blocks x 32 cols; step-renamed buffers ----------
__global__ void __launch_bounds__(NTHR) recurrent(
    const unsigned short* __restrict__ WhT_hi, const unsigned short* __restrict__ WhT_lo,
    const unsigned short* __restrict__ WhoT_hi, const unsigned short* __restrict__ WhoT_lo,
    const unsigned short* __restrict__ WoT_hi, const unsigned short* __restrict__ WoT_lo,
    const float* __restrict__ ZC,
    unsigned int* __restrict__ hq,
    unsigned int* __restrict__ hc,
    unsigned int* __restrict__ Opub,
    float* __restrict__ hist_loc,     // [NBLK][T][B][NCOL] block-private f32
    float* __restrict__ dots_g,
    const float* __restrict__ par,
    void* __restrict__ y_out,
    int* __restrict__ cnt,
    const int* __restrict__ flag)
{
  __shared__ float lds_hs[B_][NCOL + 1];
  __shared__ float lds_dt[B_][T_];
  __shared__ float lds_mu[NCOL], lds_sc[NCOL], lds_bb[NCOL];

  const int tid = threadIdx.x, wg = blockIdx.x;
  const int wv = tid >> 6, lane = tid & 63;
  const int col = lane & 15, quad = lane >> 4;
  const int j0 = wg * NCOL;
  const int bt = wv >> 1, ct = wv & 1;
  const int am0 = bt * 16;
  const int cl0 = ct * 16;
  const int jg0 = j0 + cl0;
  const float lam = par[0], eta = par[1];
  const bool isf32 = flag[0] != 0;
  float* hl = hist_loc + (size_t)wg * (T_ * B_ * NCOL);

  // zero hc[0] own cols + dots slice
  for (int d = tid; d < B_ * NCOL; d += NTHR) {
    int b = d >> 5, c = d & 31;
    astu(hc + (size_t)b * H_ + j0 + c, 0u);
  }
  for (int i = tid; i < T_ * B_ * T_ / NBLK; i += NTHR)
    astf(dots_g + (size_t)wg * (T_ * B_ * T_ / NBLK) + i, 0.f);
  rendezvous(cnt, 0);

  int slot = 1;
  for (int t = 0; t < T_; ++t) {
    const float* zb = ZC + (size_t)t * B_ * H_;
    const unsigned int* hcur = hc + (size_t)t * B_ * H_;       // virgin normal reads
    unsigned int* hqt = hq + (size_t)t * B_ * H_;
    float* dt = dots_g + (size_t)t * B_ * T_;
    // ---- stage 1: h_t = relu(zc + h_cur @ W_h), own cols ----
    {
      f32x4 acc;
#pragma unroll
      for (int r = 0; r < 4; r++)
        acc[r] = zb[(size_t)(am0 + quad * 4 + r) * H_ + jg0 + col];
      acc = mm_tile_pf(hcur, am0, WhT_hi, WhT_lo, jg0, acc, col, quad);
#pragma unroll
      for (int r = 0; r < 4; r++) {
        float v = fmaxf(acc[r], 0.f);
        int m = am0 + quad * 4 + r;
        hl[((size_t)t * B_ + m) * NCOL + cl0 + col] = v;
        astu(hqt + (size_t)m * H_ + jg0 + col, packf(v));
      }
    }
    __syncthreads();
    // ---- partial dots over own cols -> atomicAdd (batch rotated by wg) ----
    for (int d = tid; d < B_ * (t + 1); d += NTHR) {
      int b = ((d / (t + 1)) + wg) & (B_ - 1);
      int s = d % (t + 1);
      const f32x4* p = (const f32x4*)(hl + ((size_t)t * B_ + b) * NCOL);
      const f32x4* q = (const f32x4*)(hl + ((size_t)s * B_ + b) * NCOL);
      float sum = 0.f;
#pragma unroll
      for (int i = 0; i < 8; i++) {
        f32x4 a = p[i], c = q[i];
        sum += a[0] * c[0] + a[1] * c[1] + a[2] * c[2] + a[3] * c[3];
      }
      aaddf(dt + (size_t)b * T_ + s, sum);
    }
    rendezvous(cnt, slot++);
    // ---- dots[t] -> LDS (normal loads, virgin addresses) ----
    for (int d = tid; d < B_ * (t + 1); d += NTHR) {
      int b = d / (t + 1), s = d - b * (t + 1);
      lds_dt[b][s] = dt[(size_t)b * T_ + s];
    }
    // ---- hs GEMM tile: h_t @ W_h + zc (h_t via normal loads) ----
    {
      f32x4 acc;
#pragma unroll
      for (int r = 0; r < 4; r++)
        acc[r] = zb[(size_t)(am0 + quad * 4 + r) * H_ + jg0 + col];
      acc = mm_tile_pf(hqt, am0, WhT_hi, WhT_lo, jg0, acc, col, quad);
#pragma unroll
      for (int r = 0; r < 4; r++) lds_hs[am0 + quad * 4 + r][cl0 + col] = acc[r];
    }
    __syncthreads();
    // ---- attention: += eta * sum_s lam^(t-s) dots[b][s] * hl[s][b][c] ----
    for (int d = tid; d < B_ * NCOL; d += NTHR) {
      int b = d >> 5, c = d & 31;
      float a = 0.f, w = eta;
      const float* hb = hl + (size_t)b * NCOL + c;
      for (int s = t; s >= 0; --s) {
        a += w * lds_dt[b][s] * hb[(size_t)s * B_ * NCOL];
        w *= lam;
      }
      lds_hs[b][c] += a;
    }
    __syncthreads();
    // ---- batch-norm (block-local) ----
    if (tid < NCOL) {
      int c = tid;
      float sum = 0.f;
#pragma unroll
      for (int b = 0; b < B_; b++) sum += lds_hs[b][c];
      float mu = sum * (1.f / B_);
      float sq = 0.f;
#pragma unroll
      for (int b = 0; b < B_; b++) {
        float dd = lds_hs[b][c] - mu;
        sq += dd * dd;
      }
      float sig = sqrtf(sq * (1.f / B_));
      lds_mu[c] = mu;
      lds_sc[c] = par[2 + j0 + c] / sig;
      lds_bb[c] = par[2 + H_ + j0 + c];
    }
    __syncthreads();
    // ---- apply + publish hc[t+1] own cols ----
    for (int d = tid; d < B_ * NCOL; d += NTHR) {
      int b = d >> 5, c = d & 31;
      float v = (lds_hs[b][c] - lds_mu[c]) * lds_sc[c] + lds_bb[c];
      astu(hc + (size_t)(t + 1) * B_ * H_ + (size_t)b * H_ + j0 + c, packf(fmaxf(v, 0.f)));
    }
    rendezvous(cnt, slot++);
  }
  // ---- o = relu(hc[T] @ W_ho), own cols ----
  {
    const unsigned int* hfin = hc + (size_t)T_ * B_ * H_;
    f32x4 acc = {0.f, 0.f, 0.f, 0.f};
    acc = mm_tile_pf(hfin, am0, WhoT_hi, WhoT_lo, jg0, acc, col, quad);
#pragma unroll
    for (int r = 0; r < 4; r++)
      astu(Opub + (size_t)(am0 + quad * 4 + r) * H_ + jg0 + col, packf(fmaxf(acc[r], 0.f)));
  }
  rendezvous(cnt, slot++);
  // ---- y = relu(o @ W_o): 32 tiles on blocks 0..7 (normal loads of Opub) ----
  if (wg < 8) {
    int id = wg * 4 + wv;             // 0..31
    int bt2 = id & 1, jt2 = id >> 1;  // jt2 0..15
    f32x4 acc = {0.f, 0.f, 0.f, 0.f};
    acc = mm_tile_pf(Opub, bt2 * 16, WoT_hi, WoT_lo, jt2 * 16, acc, col, quad);
#pragma unroll
    for (int r = 0; r < 4; r++) {
      float v = fmaxf(acc[r], 0.f);
      size_t idx = (size_t)(bt2 * 16 + quad * 4 + r) * NOUT_ + jt2 * 16 + col;
      if (isf32) ((float*)y_out)[idx] = v;
      else       ((unsigned short*)y_out)[idx] = f2bf(v);
    }
  }
}

extern "C" void kernel_launch(void* const* d_in, const int* in_sizes, int n_in,
                              void* d_out, int out_size, void* d_ws, size_t ws_size,
                              hipStream_t stream) {
  const void* x_in = d_in[0];
  const void* W_i  = d_in[1];
  const void* W_z  = d_in[2];
  const void* W_c  = d_in[3];
  const void* W_h  = d_in[4];
  const void* W_ho = d_in[5];
  const void* W_o  = d_in[6];
  const void* lam  = d_in[7];
  const void* eta  = d_in[8];
  const void* g    = d_in[9];
  const void* bb   = d_in[10];

  char* wsp = (char*)d_ws;
  size_t off = 0;
  auto alloc = [&](size_t bytes) {
    void* p = wsp + off;
    off += (bytes + 255) & ~(size_t)255;
    return p;
  };
  int*            flag    = (int*)alloc(16);
  int*            cnt     = (int*)alloc(NSLOT * 4);
  float*          par     = (float*)alloc((2 + 2 * H_) * 4);
  unsigned int*   X_pk    = (unsigned int*)alloc((size_t)T_ * B_ * NIN_ * 4);
  unsigned short* WiT_hi  = (unsigned short*)alloc((size_t)NIN_ * H_ * 2);
  unsigned short* WiT_lo  = (unsigned short*)alloc((size_t)NIN_ * H_ * 2);
  unsigned short* WzT_hi  = (unsigned short*)alloc((size_t)H_ * H_ * 2);
  unsigned short* WzT_lo  = (unsigned short*)alloc((size_t)H_ * H_ * 2);
  unsigned short* WcT_hi  = (unsigned short*)alloc((size_t)H_ * H_ * 2);
  unsigned short* WcT_lo  = (unsigned short*)alloc((size_t)H_ * H_ * 2);
  unsigned short* WhT_hi  = (unsigned short*)alloc((size_t)H_ * H_ * 2);
  unsigned short* WhT_lo  = (unsigned short*)alloc((size_t)H_ * H_ * 2);
  unsigned short* WhoT_hi = (unsigned short*)alloc((size_t)H_ * H_ * 2);
  unsigned short* WhoT_lo = (unsigned short*)alloc((size_t)H_ * H_ * 2);
  unsigned short* WoT_hi  = (unsigned short*)alloc((size_t)H_ * NOUT_ * 2);
  unsigned short* WoT_lo  = (unsigned short*)alloc((size_t)H_ * NOUT_ * 2);
  unsigned int*   S_pk    = (unsigned int*)alloc((size_t)T_ * B_ * H_ * 4);
  unsigned int*   Z_pk    = (unsigned int*)alloc((size_t)T_ * B_ * H_ * 4);
  float*          ZC      = (float*)alloc((size_t)T_ * B_ * H_ * 4);
  unsigned int*   hq      = (unsigned int*)alloc((size_t)T_ * B_ * H_ * 4);
  unsigned int*   hc      = (unsigned int*)alloc((size_t)(T_ + 1) * B_ * H_ * 4);
  unsigned int*   Opub    = (unsigned int*)alloc((size_t)B_ * H_ * 4);
  float*          histloc = (float*)alloc((size_t)NBLK * T_ * B_ * NCOL * 4);
  float*          dots_g  = (float*)alloc((size_t)T_ * B_ * T_ * 4);
  (void)ws_size; (void)in_sizes; (void)n_in; (void)out_size;

  // 1. detect dtype + zero counters; x -> relu+pack; params
  init_detect<<<1, 256, 0, stream>>>((const unsigned short*)x_in, flag, cnt);
  pack_relu_x<<<256, 256, 0, stream>>>(x_in, X_pk, T_ * B_ * NIN_, flag);
  prep_params<<<4, 256, 0, stream>>>(lam, eta, g, bb, par, flag);

  // 2. transpose + hi/lo split weights -> bf16 [N][K]
  split_transpose<<<dim3(H_ / 32, NIN_ / 32), 256, 0, stream>>>(W_i, WiT_hi, WiT_lo, NIN_, H_, flag);
  split_transpose<<<dim3(H_ / 32, H_ / 32), 256, 0, stream>>>(W_z, WzT_hi, WzT_lo, H_, H_, flag);
  split_transpose<<<dim3(H_ / 32, H_ / 32), 256, 0, stream>>>(W_c, WcT_hi, WcT_lo, H_, H_, flag);
  split_transpose<<<dim3(H_ / 32, H_ / 32), 256, 0, stream>>>(W_h, WhT_hi, WhT_lo, H_, H_, flag);
  split_transpose<<<dim3(H_ / 32, H_ / 32), 256, 0, stream>>>(W_ho, WhoT_hi, WhoT_lo, H_, H_, flag);
  split_transpose<<<dim3(NOUT_ / 32, H_ / 32), 256, 0, stream>>>(W_o, WoT_hi, WoT_lo, H_, NOUT_, flag);

  // 3. phase A (packed): S = relu(X@W_i); Z = relu(S@W_z); ZC = Z@W_c (f32)
  gemmA_pk<NIN_, H_, 1><<<1024, 256, 0, stream>>>(X_pk, WiT_hi, WiT_lo, S_pk);
  gemmA_pk<H_,   H_, 1><<<1024, 256, 0, stream>>>(S_pk, WzT_hi, WzT_lo, Z_pk);
  gemmA_pk<H_,   H_, 0><<<1024, 256, 0, stream>>>(Z_pk, WcT_hi, WcT_lo, ZC);

  // 4. phase B: recurrence + readout, step-renamed buffers + relaxed rendezvous
  recurrent<<<NBLK, NTHR, 0, stream>>>(WhT_hi, WhT_lo, WhoT_hi, WhoT_lo, WoT_hi, WoT_lo,
                                       ZC, hq, hc, Opub, histloc, dots_g,
                                       par, d_out, cnt, flag);
}

// Round 12
// 1247.132 us; speedup vs baseline: 2.8369x; 1.3206x over previous
//
#include <hip/hip_runtime.h>
#include <hip/hip_bf16.h>

#define T_   32
#define B_   32
#define NIN_ 512
#define H_   1024
#define NOUT_ 256
#define NBLK 32
#define NTHR 1024
#define NCOL 32
#define NSLOT 80

typedef short bf16x8 __attribute__((ext_vector_type(8)));
typedef float f32x4  __attribute__((ext_vector_type(4)));
typedef unsigned int u32x4 __attribute__((ext_vector_type(4)));

__device__ __forceinline__ float bf2f(unsigned short u) {
  union { unsigned int i; float f; } x; x.i = ((unsigned int)u) << 16; return x.f;
}
__device__ __forceinline__ unsigned short f2bf(float f) {
  __hip_bfloat16 h = __float2bfloat16(f);
  return *reinterpret_cast<unsigned short*>(&h);
}
__device__ __forceinline__ unsigned int packf(float v) {
  unsigned short h = f2bf(v);
  unsigned short l = f2bf(v - bf2f(h));
  return ((unsigned int)h << 16) | l;
}
__device__ __forceinline__ void unpack8v(u32x4 a, u32x4 b, bf16x8& hi, bf16x8& lo) {
  unsigned int t[8] = {a[0], a[1], a[2], a[3], b[0], b[1], b[2], b[3]};
  union { bf16x8 v; unsigned int u[4]; } H, L;
#pragma unroll
  for (int j = 0; j < 4; j++) {
    unsigned int e = t[2 * j], o = t[2 * j + 1];
    H.u[j] = (o & 0xFFFF0000u) | (e >> 16);
    L.u[j] = (o << 16) | (e & 0xFFFFu);
  }
  hi = H.v; lo = L.v;
}

// ---- publish primitives: relaxed agent-scope atomics ----
__device__ __forceinline__ void astu(unsigned int* p, unsigned int v) {
  __hip_atomic_store(p, v, __ATOMIC_RELAXED, __HIP_MEMORY_SCOPE_AGENT);
}
__device__ __forceinline__ void astf(float* p, float v) {
  __hip_atomic_store(p, v, __ATOMIC_RELAXED, __HIP_MEMORY_SCOPE_AGENT);
}
__device__ __forceinline__ void aaddf(float* p, float v) {
  __hip_atomic_fetch_add(p, v, __ATOMIC_RELAXED, __HIP_MEMORY_SCOPE_AGENT);
}

// ---- rendezvous: fresh slot; relaxed arrival + relaxed spin ----
__device__ __forceinline__ void rendezvous(int* cnt, int slot) {
  __syncthreads();
  if (threadIdx.x == 0) {
    __hip_atomic_fetch_add(&cnt[slot], 1, __ATOMIC_RELAXED, __HIP_MEMORY_SCOPE_AGENT);
    while (__hip_atomic_load(&cnt[slot], __ATOMIC_RELAXED, __HIP_MEMORY_SCOPE_AGENT) < NBLK)
      __builtin_amdgcn_s_sleep(1);
    __atomic_signal_fence(__ATOMIC_ACQUIRE);
  }
  __syncthreads();
}

// ---------- dtype detect + counter init ----------
__global__ void init_detect(const unsigned short* __restrict__ x_raw,
                            int* __restrict__ flag, int* __restrict__ cnt) {
  __shared__ int bad;
  if (threadIdx.x == 0) bad = 0;
  __syncthreads();
  int c = 0;
  for (int i = threadIdx.x; i < 2048; i += 256) {
    float v = bf2f(x_raw[i]);
    if (!(fabsf(v) < 1e9f)) c++;
  }
  if (c) atomicAdd(&bad, 1);
  __syncthreads();
  if (threadIdx.x == 0) flag[0] = bad ? 1 : 0;  // 1 = inputs are f32
  for (int i = threadIdx.x; i < NSLOT; i += 256)
    __hip_atomic_store(&cnt[i], 0, __ATOMIC_RELAXED, __HIP_MEMORY_SCOPE_AGENT);
}

// ---------- x -> relu + pack ----------
__global__ void pack_relu_x(const void* __restrict__ src, unsigned int* __restrict__ dst,
                            int n, const int* __restrict__ flag) {
  bool isf32 = flag[0] != 0;
  for (int i = blockIdx.x * 256 + threadIdx.x; i < n; i += gridDim.x * 256) {
    float v = isf32 ? ((const float*)src)[i] : bf2f(((const unsigned short*)src)[i]);
    dst[i] = packf(fmaxf(v, 0.f));
  }
}

// ---------- params -> float: [lam, eta, g[1024], b[1024]] ----------
__global__ void prep_params(const void* lam, const void* eta, const void* g, const void* b,
                            float* __restrict__ par, const int* __restrict__ flag) {
  bool isf32 = flag[0] != 0;
  int t = blockIdx.x * 256 + threadIdx.x;
  if (t == 0) {
    par[0] = isf32 ? ((const float*)lam)[0] : bf2f(((const unsigned short*)lam)[0]);
    par[1] = isf32 ? ((const float*)eta)[0] : bf2f(((const unsigned short*)eta)[0]);
  }
  if (t < H_) {
    par[2 + t]      = isf32 ? ((const float*)g)[t] : bf2f(((const unsigned short*)g)[t]);
    par[2 + H_ + t] = isf32 ? ((const float*)b)[t] : bf2f(((const unsigned short*)b)[t]);
  }
}

// ---------- transpose + hi/lo split: W [R][C] -> bf16 [C][R] ----------
__global__ void split_transpose(const void* __restrict__ in,
                                unsigned short* __restrict__ out_hi,
                                unsigned short* __restrict__ out_lo,
                                int R, int C, const int* __restrict__ flag) {
  __shared__ unsigned short thi[32][33], tlo[32][33];
  bool isf32 = flag[0] != 0;
  int c0 = blockIdx.x * 32, r0 = blockIdx.y * 32;
  int tx = threadIdx.x & 31, ty = threadIdx.x >> 5;
  for (int i = ty; i < 32; i += 8) {
    size_t idx = (size_t)(r0 + i) * C + c0 + tx;
    float v = isf32 ? ((const float*)in)[idx] : bf2f(((const unsigned short*)in)[idx]);
    unsigned short h = f2bf(v);
    thi[i][tx] = h;
    tlo[i][tx] = f2bf(v - bf2f(h));
  }
  __syncthreads();
  for (int i = ty; i < 32; i += 8) {
    out_hi[(size_t)(c0 + i) * R + r0 + tx] = thi[tx][i];
    out_lo[(size_t)(c0 + i) * R + r0 + tx] = tlo[tx][i];
  }
}

// ---------- phase-A GEMM on packed A: out = relu+pack (1) or f32 (0) ----------
template<int K, int N, int OUTMODE>
__global__ void gemmA_pk(const unsigned int* __restrict__ A,
                         const unsigned short* __restrict__ BT_hi,
                         const unsigned short* __restrict__ BT_lo,
                         void* __restrict__ C) {
  int wave = (blockIdx.x * blockDim.x + threadIdx.x) >> 6;
  int lane = threadIdx.x & 63;
  const int ntj = N >> 4;
  int mt = wave / ntj, jt = wave - mt * ntj;
  int col = lane & 15, quad = lane >> 4;
  const unsigned int*   ap = A     + (size_t)(mt * 16 + col) * K + quad * 8;
  const unsigned short* bh = BT_hi + (size_t)(jt * 16 + col) * K + quad * 8;
  const unsigned short* bl = BT_lo + (size_t)(jt * 16 + col) * K + quad * 8;
  f32x4 acc = {0.f, 0.f, 0.f, 0.f};
#pragma unroll 4
  for (int kk = 0; kk < K; kk += 32) {
    bf16x8 ahi, alo;
    unpack8v(*(const u32x4*)(ap + kk), *(const u32x4*)(ap + kk + 4), ahi, alo);
    bf16x8 vh = *(const bf16x8*)(bh + kk);
    bf16x8 vl = *(const bf16x8*)(bl + kk);
    acc = __builtin_amdgcn_mfma_f32_16x16x32_bf16(ahi, vh, acc, 0, 0, 0);
    acc = __builtin_amdgcn_mfma_f32_16x16x32_bf16(alo, vh, acc, 0, 0, 0);
    acc = __builtin_amdgcn_mfma_f32_16x16x32_bf16(ahi, vl, acc, 0, 0, 0);
  }
#pragma unroll
  for (int r = 0; r < 4; r++) {
    size_t idx = (size_t)(mt * 16 + quad * 4 + r) * N + jt * 16 + col;
    if (OUTMODE) ((unsigned int*)C)[idx] = packf(fmaxf(acc[r], 0.f));
    else         ((float*)C)[idx] = acc[r];
  }
}

// ---- K-split partial tile: 256-wide K chunk, all 16 A-loads issued up-front ----
__device__ __forceinline__ f32x4 mm_part(
    const unsigned int* __restrict__ A, int am0, int k0,
    const unsigned short* __restrict__ BH, const unsigned short* __restrict__ BL,
    int bj0, int col, int quad) {
  const unsigned int*   ap = A  + (size_t)(am0 + col) * H_ + k0 + quad * 8;
  const unsigned short* bh = BH + (size_t)(bj0 + col) * H_ + k0 + quad * 8;
  const unsigned short* bl = BL + (size_t)(bj0 + col) * H_ + k0 + quad * 8;
  u32x4 ab[16];
#pragma unroll
  for (int i = 0; i < 8; i++) {
    ab[2 * i]     = *(const u32x4*)(ap + 32 * i);
    ab[2 * i + 1] = *(const u32x4*)(ap + 32 * i + 4);
  }
  f32x4 acc = {0.f, 0.f, 0.f, 0.f};
#pragma unroll
  for (int i = 0; i < 8; i++) {
    bf16x8 ahi, alo;
    unpack8v(ab[2 * i], ab[2 * i + 1], ahi, alo);
    bf16x8 vh = *(const bf16x8*)(bh + 32 * i);
    bf16x8 vl = *(const bf16x8*)(bl + 32 * i);
    acc = __builtin_amdgcn_mfma_f32_16x16x32_bf16(ahi, vh, acc, 0, 0, 0);
    acc = __builtin_amdgcn_mfma_f32_16x16x32_bf16(alo, vh, acc, 0, 0, 0);
    acc = __builtin_amdgcn_mfma_f32_16x16x32_bf16(ahi, vl, acc, 0, 0, 0);
  }
  return acc;
}
// full-K tile (for final y GEMM)
__device__ __forceinline__ f32x4 mm_tile_pf(
    const unsigned int* __restrict__ A, int am0,
    const unsigned short* __restrict__ BH, const unsigned short* __restrict__ BL,
    int bj0, f32x4 acc, int col, int quad) {
#pragma unroll 1
  for (int kk = 0; kk < H_; kk += 256) {
    f32x4 p = mm_part(A, am0, kk, BH, BL, bj0, col, quad);
    acc[0] += p[0]; acc[1] += p[1]; acc[2] += p[2]; acc[3] += p[3];
  }
  return acc;
}

// ---------- recurrent: 32 blocks x 1024 thr; K-split GEMMs; step-renamed buffers ----------
__global__ void __launch_bounds__(NTHR) recurrent(
    const unsigned short* __restrict__ WhT_hi, const unsigned short* __restrict__ WhT_lo,
    const unsigned short* __restrict__ WhoT_hi, const unsigned short* __restrict__ WhoT_lo,
    const unsigned short* __restrict__ WoT_hi, const unsigned short* __restrict__ WoT_lo,
    const float* __restrict__ ZC,
    unsigned int* __restrict__ hq,
    unsigned int* __restrict__ hc,
    unsigned int* __restrict__ Opub,
    float* __restrict__ hist_loc,     // [NBLK][T][B][NCOL] block-private f32
    float* __restrict__ dots_g,
    const float* __restrict__ par,
    void* __restrict__ y_out,
    int* __restrict__ cnt,
    const int* __restrict__ flag)
{
  __shared__ f32x4 red[16][64];               // 16 KB: per-wave partial accs
  __shared__ float lds_hs[B_][NCOL + 1];
  __shared__ float lds_dt[B_][T_];
  __shared__ float lds_mu[NCOL], lds_sc[NCOL], lds_bb[NCOL];

  const int tid = threadIdx.x, wg = blockIdx.x;
  const int wv = tid >> 6, lane = tid & 63;
  const int col = lane & 15, quad = lane >> 4;
  const int j0 = wg * NCOL;
  const int tile = wv & 3, kp = wv >> 2;      // 4 tiles x 4 K-parts
  const int am0 = (tile >> 1) * 16;
  const int cl0 = (tile & 1) * 16;
  const int jg0 = j0 + cl0;
  const int k0 = kp * 256;
  const float lam = par[0], eta = par[1];
  const bool isf32 = flag[0] != 0;
  float* hl = hist_loc + (size_t)wg * (T_ * B_ * NCOL);

  // zero hc[0] own cols + dots slice
  for (int d = tid; d < B_ * NCOL; d += NTHR) {
    int b = d >> 5, c = d & 31;
    astu(hc + (size_t)b * H_ + j0 + c, 0u);
  }
  for (int i = tid; i < T_ * B_ * T_ / NBLK; i += NTHR)
    astf(dots_g + (size_t)wg * (T_ * B_ * T_ / NBLK) + i, 0.f);
  rendezvous(cnt, 0);

  int slot = 1;
  for (int t = 0; t < T_; ++t) {
    const float* zb = ZC + (size_t)t * B_ * H_;
    const unsigned int* hcur = hc + (size_t)t * B_ * H_;
    unsigned int* hqt = hq + (size_t)t * B_ * H_;
    float* dt = dots_g + (size_t)t * B_ * T_;
    // ---- stage 1: h_t = relu(zc + h_cur @ W_h) — K-split across 16 waves ----
    red[wv][lane] = mm_part(hcur, am0, k0, WhT_hi, WhT_lo, jg0, col, quad);
    __syncthreads();
    if (wv < 4) {
      int a0 = (wv >> 1) * 16, c0 = (wv & 1) * 16, jj = j0 + c0;
      f32x4 s0 = red[wv][lane], s1 = red[wv + 4][lane],
            s2 = red[wv + 8][lane], s3 = red[wv + 12][lane];
#pragma unroll
      for (int r = 0; r < 4; r++) {
        float v = zb[(size_t)(a0 + quad * 4 + r) * H_ + jj + col]
                + ((s0[r] + s1[r]) + (s2[r] + s3[r]));
        v = fmaxf(v, 0.f);
        int m = a0 + quad * 4 + r;
        hl[((size_t)t * B_ + m) * NCOL + c0 + col] = v;
        astu(hqt + (size_t)m * H_ + jj + col, packf(v));
      }
    }
    __syncthreads();
    // ---- partial dots over own cols -> atomicAdd (batch rotated by wg) ----
    for (int d = tid; d < B_ * (t + 1); d += NTHR) {
      int b = ((d / (t + 1)) + wg) & (B_ - 1);
      int s = d % (t + 1);
      const f32x4* p = (const f32x4*)(hl + ((size_t)t * B_ + b) * NCOL);
      const f32x4* q = (const f32x4*)(hl + ((size_t)s * B_ + b) * NCOL);
      float sum = 0.f;
#pragma unroll
      for (int i = 0; i < 8; i++) {
        f32x4 a = p[i], c = q[i];
        sum += a[0] * c[0] + a[1] * c[1] + a[2] * c[2] + a[3] * c[3];
      }
      aaddf(dt + (size_t)b * T_ + s, sum);
    }
    rendezvous(cnt, slot++);
    // ---- dots[t] -> LDS ----
    for (int d = tid; d < B_ * (t + 1); d += NTHR) {
      int b = d / (t + 1), s = d - b * (t + 1);
      lds_dt[b][s] = dt[(size_t)b * T_ + s];
    }
    // ---- hs GEMM: h_t @ W_h + zc — K-split ----
    red[wv][lane] = mm_part(hqt, am0, k0, WhT_hi, WhT_lo, jg0, col, quad);
    __syncthreads();
    if (wv < 4) {
      int a0 = (wv >> 1) * 16, c0 = (wv & 1) * 16, jj = j0 + c0;
      f32x4 s0 = red[wv][lane], s1 = red[wv + 4][lane],
            s2 = red[wv + 8][lane], s3 = red[wv + 12][lane];
#pragma unroll
      for (int r = 0; r < 4; r++)
        lds_hs[a0 + quad * 4 + r][c0 + col] =
            zb[(size_t)(a0 + quad * 4 + r) * H_ + jj + col]
            + ((s0[r] + s1[r]) + (s2[r] + s3[r]));
    }
    __syncthreads();
    // ---- attention: += eta * sum_s lam^(t-s) dots[b][s] * hl[s][b][c] ----
    for (int d = tid; d < B_ * NCOL; d += NTHR) {
      int b = d >> 5, c = d & 31;
      float a = 0.f, w = eta;
      const float* hb = hl + (size_t)b * NCOL + c;
      for (int s = t; s >= 0; --s) {
        a += w * lds_dt[b][s] * hb[(size_t)s * B_ * NCOL];
        w *= lam;
      }
      lds_hs[b][c] += a;
    }
    __syncthreads();
    // ---- batch-norm (block-local) ----
    if (tid < NCOL) {
      int c = tid;
      float sum = 0.f;
#pragma unroll
      for (int b = 0; b < B_; b++) sum += lds_hs[b][c];
      float mu = sum * (1.f / B_);
      float sq = 0.f;
#pragma unroll
      for (int b = 0; b < B_; b++) {
        float dd = lds_hs[b][c] - mu;
        sq += dd * dd;
      }
      float sig = sqrtf(sq * (1.f / B_));
      lds_mu[c] = mu;
      lds_sc[c] = par[2 + j0 + c] / sig;
      lds_bb[c] = par[2 + H_ + j0 + c];
    }
    __syncthreads();
    // ---- apply + publish hc[t+1] own cols ----
    for (int d = tid; d < B_ * NCOL; d += NTHR) {
      int b = d >> 5, c = d & 31;
      float v = (lds_hs[b][c] - lds_mu[c]) * lds_sc[c] + lds_bb[c];
      astu(hc + (size_t)(t + 1) * B_ * H_ + (size_t)b * H_ + j0 + c, packf(fmaxf(v, 0.f)));
    }
    rendezvous(cnt, slot++);
  }
  // ---- o = relu(hc[T] @ W_ho), own cols — K-split ----
  {
    const unsigned int* hfin = hc + (size_t)T_ * B_ * H_;
    red[wv][lane] = mm_part(hfin, am0, k0, WhoT_hi, WhoT_lo, jg0, col, quad);
    __syncthreads();
    if (wv < 4) {
      int a0 = (wv >> 1) * 16, c0 = (wv & 1) * 16, jj = j0 + c0;
      f32x4 s0 = red[wv][lane], s1 = red[wv + 4][lane],
            s2 = red[wv + 8][lane], s3 = red[wv + 12][lane];
#pragma unroll
      for (int r = 0; r < 4; r++) {
        float v = fmaxf((s0[r] + s1[r]) + (s2[r] + s3[r]), 0.f);
        astu(Opub + (size_t)(a0 + quad * 4 + r) * H_ + jj + col, packf(v));
      }
    }
  }
  rendezvous(cnt, slot++);
  // ---- y = relu(o @ W_o): 32 tiles on blocks 0..1 (full-K) ----
  if (wg < 2) {
    int id = wg * 16 + wv;            // 0..31
    int bt2 = id & 1, jt2 = id >> 1;  // jt2 0..15
    f32x4 acc = {0.f, 0.f, 0.f, 0.f};
    acc = mm_tile_pf(Opub, bt2 * 16, WoT_hi, WoT_lo, jt2 * 16, acc, col, quad);
#pragma unroll
    for (int r = 0; r < 4; r++) {
      float v = fmaxf(acc[r], 0.f);
      size_t idx = (size_t)(bt2 * 16 + quad * 4 + r) * NOUT_ + jt2 * 16 + col;
      if (isf32) ((float*)y_out)[idx] = v;
      else       ((unsigned short*)y_out)[idx] = f2bf(v);
    }
  }
}

extern "C" void kernel_launch(void* const* d_in, const int* in_sizes, int n_in,
                              void* d_out, int out_size, void* d_ws, size_t ws_size,
                              hipStream_t stream) {
  const void* x_in = d_in[0];
  const void* W_i  = d_in[1];
  const void* W_z  = d_in[2];
  const void* W_c  = d_in[3];
  const void* W_h  = d_in[4];
  const void* W_ho = d_in[5];
  const void* W_o  = d_in[6];
  const void* lam  = d_in[7];
  const void* eta  = d_in[8];
  const void* g    = d_in[9];
  const void* bb   = d_in[10];

  char* wsp = (char*)d_ws;
  size_t off = 0;
  auto alloc = [&](size_t bytes) {
    void* p = wsp + off;
    off += (bytes + 255) & ~(size_t)255;
    return p;
  };
  int*            flag    = (int*)alloc(16);
  int*            cnt     = (int*)alloc(NSLOT * 4);
  float*          par     = (float*)alloc((2 + 2 * H_) * 4);
  unsigned int*   X_pk    = (unsigned int*)alloc((size_t)T_ * B_ * NIN_ * 4);
  unsigned short* WiT_hi  = (unsigned short*)alloc((size_t)NIN_ * H_ * 2);
  unsigned short* WiT_lo  = (unsigned short*)alloc((size_t)NIN_ * H_ * 2);
  unsigned short* WzT_hi  = (unsigned short*)alloc((size_t)H_ * H_ * 2);
  unsigned short* WzT_lo  = (unsigned short*)alloc((size_t)H_ * H_ * 2);
  unsigned short* WcT_hi  = (unsigned short*)alloc((size_t)H_ * H_ * 2);
  unsigned short* WcT_lo  = (unsigned short*)alloc((size_t)H_ * H_ * 2);
  unsigned short* WhT_hi  = (unsigned short*)alloc((size_t)H_ * H_ * 2);
  unsigned short* WhT_lo  = (unsigned short*)alloc((size_t)H_ * H_ * 2);
  unsigned short* WhoT_hi = (unsigned short*)alloc((size_t)H_ * H_ * 2);
  unsigned short* WhoT_lo = (unsigned short*)alloc((size_t)H_ * H_ * 2);
  unsigned short* WoT_hi  = (unsigned short*)alloc((size_t)H_ * NOUT_ * 2);
  unsigned short* WoT_lo  = (unsigned short*)alloc((size_t)H_ * NOUT_ * 2);
  unsigned int*   S_pk    = (unsigned int*)alloc((size_t)T_ * B_ * H_ * 4);
  unsigned int*   Z_pk    = (unsigned int*)alloc((size_t)T_ * B_ * H_ * 4);
  float*          ZC      = (float*)alloc((size_t)T_ * B_ * H_ * 4);
  unsigned int*   hq      = (unsigned int*)alloc((size_t)T_ * B_ * H_ * 4);
  unsigned int*   hc      = (unsigned int*)alloc((size_t)(T_ + 1) * B_ * H_ * 4);
  unsigned int*   Opub    = (unsigned int*)alloc((size_t)B_ * H_ * 4);
  float*          histloc = (float*)alloc((size_t)NBLK * T_ * B_ * NCOL * 4);
  float*          dots_g  = (float*)alloc((size_t)T_ * B_ * T_ * 4);
  (void)ws_size; (void)in_sizes; (void)n_in; (void)out_size;

  // 1. detect dtype + zero counters; x -> relu+pack; params
  init_detect<<<1, 256, 0, stream>>>((const unsigned short*)x_in, flag, cnt);
  pack_relu_x<<<256, 256, 0, stream>>>(x_in, X_pk, T_ * B_ * NIN_, flag);
  prep_params<<<4, 256, 0, stream>>>(lam, eta, g, bb, par, flag);

  // 2. transpose + hi/lo split weights -> bf16 [N][K]
  split_transpose<<<dim3(H_ / 32, NIN_ / 32), 256, 0, stream>>>(W_i, WiT_hi, WiT_lo, NIN_, H_, flag);
  split_transpose<<<dim3(H_ / 32, H_ / 32), 256, 0, stream>>>(W_z, WzT_hi, WzT_lo, H_, H_, flag);
  split_transpose<<<dim3(H_ / 32, H_ / 32), 256, 0, stream>>>(W_c, WcT_hi, WcT_lo, H_, H_, flag);
  split_transpose<<<dim3(H_ / 32, H_ / 32), 256, 0, stream>>>(W_h, WhT_hi, WhT_lo, H_, H_, flag);
  split_transpose<<<dim3(H_ / 32, H_ / 32), 256, 0, stream>>>(W_ho, WhoT_hi, WhoT_lo, H_, H_, flag);
  split_transpose<<<dim3(NOUT_ / 32, H_ / 32), 256, 0, stream>>>(W_o, WoT_hi, WoT_lo, H_, NOUT_, flag);

  // 3. phase A (packed): S = relu(X@W_i); Z = relu(S@W_z); ZC = Z@W_c (f32)
  gemmA_pk<NIN_, H_, 1><<<1024, 256, 0, stream>>>(X_pk, WiT_hi, WiT_lo, S_pk);
  gemmA_pk<H_,   H_, 1><<<1024, 256, 0, stream>>>(S_pk, WzT_hi, WzT_lo, Z_pk);
  gemmA_pk<H_,   H_, 0><<<1024, 256, 0, stream>>>(Z_pk, WcT_hi, WcT_lo, ZC);

  // 4. phase B: recurrence + readout, K-split high-concurrency GEMMs
  recurrent<<<NBLK, NTHR, 0, stream>>>(WhT_hi, WhT_lo, WhoT_hi, WhoT_lo, WoT_hi, WoT_lo,
                                       ZC, hq, hc, Opub, histloc, dots_g,
                                       par, d_out, cnt, flag);
}